// Round 1
// baseline (818.400 us; speedup 1.0000x reference)
//
#include <hip/hip_runtime.h>

// VisualDepthAttention on MI355X (gfx950) — round 3.
// R2 post-mortem: 408 us/dispatch, MfmaUtil 8.8%, VALUBusy 21%, Occupancy 45%.
// 152KB LDS -> 1 block/CU; 16 waves lockstep through 6 barriers -> ~70% stall. R1->R2
// (4x waves in-block) barely helped => co-phased waves can't hide each other's stalls.
// R3: split at the qkv boundary.
//   K1: GEMM1 (stage x + xs@Wcat), epilogue -> global qp/kp (row-major bf16), vp
//       (frag-linear bf16, proven layout), dp (depth fp32). LDS 37.9KB.
//   K2: attention+GEMM2, wave=head, 512 thr, LDS 71.9KB -> 2 independent blocks/CU
//       (cross-block phase overlap). GEMM2 rebalanced to (nt, m-half) tasks (max 5 vs
//       old 2x convoy on wave0). 3 barriers/block.
// Workspace chunked by ws_size (99,072 B/window); fallback = R2 fused kernel.

#define D1    257
#define NTOK  64
#define KT    9      // K padded to 288 = 9*32
#define NT_CAT 49    // Wcat N = 784 = 49*16
#define NT_OUT 17    // Wout N = 272 = 17*16
#define SCALE 0.17677669529663687f

// ---- fused fallback kernel LDS layout (unchanged from R2) ----
#define XS_OFF    0
#define XS_STRIDE 296
#define OC_STRIDE 296
#define QS_OFF    37888
#define QK_STRIDE 264
#define AT_STRIDE 68
#define KS_OFF    72704
#define VS_OFF    106496
#define DS_OFF    139264
#define DS_STRIDE 65
#define QD_OFF    155904
#define KD_OFF    156160
#define VD_OFF    156416
#define LDS_SIZE  156672

// ---- K2 LDS layout: oc [64][296] bf16 | dsum [64][65] f32 | at 8x[16][68] bf16 ----
#define K2_OC_OFF 0
#define K2_DS_OFF 37888
#define K2_AT_OFF 54528
#define K2_LDS    71936

#define WCAT_ELEMS (KT * NT_CAT * 512)   // 225792 bf16
#define WOUT_ELEMS (KT * NT_OUT * 512)   // 78336 bf16

using bf16x8 = __attribute__((ext_vector_type(8))) short;
using s16x4  = __attribute__((ext_vector_type(4))) short;
using f32x4  = __attribute__((ext_vector_type(4))) float;

__device__ __forceinline__ short f2b(float f) {
  unsigned u = __float_as_uint(f);
  u = (u + 0x7FFFu + ((u >> 16) & 1u)) >> 16;   // RNE
  return (short)u;
}

__device__ __forceinline__ f32x4 mfma16(bf16x8 a, bf16x8 b, f32x4 c) {
  return __builtin_amdgcn_mfma_f32_16x16x32_bf16(a, b, c, 0, 0, 0);
}

__global__ void prep_weights(const float* __restrict__ Wqv, const float* __restrict__ Wkv,
                             const float* __restrict__ Wvv, const float* __restrict__ Wqd,
                             const float* __restrict__ Wkd, const float* __restrict__ Wvd,
                             const float* __restrict__ Wout,
                             short* __restrict__ wcatp, short* __restrict__ woutp) {
  int idx = blockIdx.x * 256 + threadIdx.x;
  if (idx < WCAT_ELEMS) {
    int j = idx & 7, lane = (idx >> 3) & 63, rest = idx >> 9;
    int nt = rest % NT_CAT, kt = rest / NT_CAT;
    int k = 32 * kt + (lane >> 4) * 8 + j;
    int n = 16 * nt + (lane & 15);
    float v = 0.f;
    if (k < D1) {
      if (n < 256)       v = Wqv[k * 256 + n] * SCALE;
      else if (n < 512)  v = Wkv[k * 256 + (n - 256)];
      else if (n < 768)  v = Wvv[k * 256 + (n - 512)];
      else if (n == 768) v = Wqd[k] * SCALE;
      else if (n == 769) v = Wkd[k];
      else if (n == 770) v = Wvd[k];
    }
    wcatp[idx] = f2b(v);
  } else {
    int i2 = idx - WCAT_ELEMS;
    int j = i2 & 7, lane = (i2 >> 3) & 63, rest = i2 >> 9;
    int nt = rest % NT_OUT, kt = rest / NT_OUT;
    int k = 32 * kt + (lane >> 4) * 8 + j;
    int n = 16 * nt + (lane & 15);
    float v = (k < D1 && n < D1) ? Wout[k * D1 + n] : 0.f;
    woutp[i2] = f2b(v);
  }
}

// ======================= K1: GEMM1 -> global qkv =======================
__global__ __launch_bounds__(1024)
void vda_k1(const float* __restrict__ x, const short* __restrict__ wcatp,
            short* __restrict__ qp, short* __restrict__ kp, short* __restrict__ vp,
            float* __restrict__ dp, int win0) {
  __shared__ short xs[64 * XS_STRIDE];   // 37,888 B

  const int tid  = threadIdx.x;
  const int lane = tid & 63;
  const int w    = tid >> 6;
  const int m    = lane & 15;
  const int q    = lane >> 4;
  const int q8   = q * 8;
  const int widx = blockIdx.x;
  const int win  = win0 + widx;

  // stage x (64x257 fp32 -> bf16), zero K-pad cols
  for (int i = tid; i < 64 * 39; i += 1024) {
    int r = i / 39, c = 257 + (i % 39);
    xs[r * XS_STRIDE + c] = 0;
  }
  {
    const float4* xw4 = (const float4*)(x + (size_t)win * (NTOK * D1));
    for (int f4 = tid; f4 < 4112; f4 += 1024) {
      float4 v = xw4[f4];
      float vals[4] = {v.x, v.y, v.z, v.w};
      int o0 = f4 * 4;
      int r0 = o0 / D1, c0 = o0 - r0 * D1;
#pragma unroll
      for (int jj = 0; jj < 4; ++jj) {
        int c = c0 + jj, r = r0;
        if (c >= D1) { c -= D1; r += 1; }
        xs[r * XS_STRIDE + c] = f2b(vals[jj]);
      }
    }
  }
  __syncthreads();

  // C = xs[64x288] @ Wcat[288x784]; kt-outer, acc resident. Wave w: nt in {w,w+16,w+32,w+48}.
  f32x4 acc[4][4];
#pragma unroll
  for (int t = 0; t < 4; ++t)
#pragma unroll
    for (int mt = 0; mt < 4; ++mt) acc[t][mt] = f32x4{0.f, 0.f, 0.f, 0.f};

  for (int kt = 0; kt < KT; ++kt) {
    bf16x8 af[4];
#pragma unroll
    for (int mt = 0; mt < 4; ++mt)
      af[mt] = *(const bf16x8*)&xs[(16 * mt + m) * XS_STRIDE + 32 * kt + q8];
#pragma unroll
    for (int t = 0; t < 4; ++t) {
      int nt = w + 16 * t;
      if (nt < NT_CAT) {
        bf16x8 bfr = *(const bf16x8*)(wcatp + ((size_t)(kt * NT_CAT + nt) * 64 + lane) * 8);
#pragma unroll
        for (int mt = 0; mt < 4; ++mt)
          acc[t][mt] = mfma16(af[mt], bfr, acc[t][mt]);
      }
    }
  }

  // epilogue -> global. Q/K row-major [win][64][256] bf16; V frag-linear; depth fp32.
  short* qpw = qp + (size_t)widx * 16384;
  short* kpw = kp + (size_t)widx * 16384;
  short* vpw = vp + (size_t)widx * 16384;
  float* dpw = dp + (size_t)widx * 192;
#pragma unroll
  for (int t = 0; t < 4; ++t) {
    int nt = w + 16 * t;
    if (nt >= NT_CAT) continue;
    int c = nt * 16 + m;
    if (c < 256) {
#pragma unroll
      for (int mt = 0; mt < 4; ++mt)
#pragma unroll
        for (int r = 0; r < 4; ++r)
          qpw[(16 * mt + 4 * q + r) * 256 + c] = f2b(acc[t][mt][r]);
    } else if (c < 512) {
      int cc = c - 256;
#pragma unroll
      for (int mt = 0; mt < 4; ++mt)
#pragma unroll
        for (int r = 0; r < 4; ++r)
          kpw[(16 * mt + 4 * q + r) * 256 + cc] = f2b(acc[t][mt][r]);
    } else if (c < 768) {
      // frag = (d>>4)*2 + (token>>5), slot = (((token>>3)&3)*16 + (d&15))*8 + (token&7)
#pragma unroll
      for (int mt = 0; mt < 4; ++mt) {
        int frag = (nt - 32) * 2 + (mt >> 1);
        int q2 = (2 * mt + (q >> 1)) & 3;
        int j0 = 4 * (q & 1);
        s16x4 pk;
#pragma unroll
        for (int r = 0; r < 4; ++r) pk[r] = f2b(acc[t][mt][r]);
        *(s16x4*)&vpw[frag * 512 + (q2 * 16 + m) * 8 + j0] = pk;
      }
    } else if (m < 3) {                  // depth cols 768..770 -> dp[win][3][64]
      float* dst = dpw + m * 64;
#pragma unroll
      for (int mt = 0; mt < 4; ++mt)
#pragma unroll
        for (int r = 0; r < 4; ++r)
          dst[16 * mt + 4 * q + r] = acc[t][mt][r];
    }
  }
}

// ======================= K2: attention + GEMM2 (wave = head) =======================
__global__ __launch_bounds__(512, 4)
void vda_k2(const short* __restrict__ qp, const short* __restrict__ kp,
            const short* __restrict__ vp, const float* __restrict__ dp,
            const short* __restrict__ woutp, float* __restrict__ out, int win0) {
  extern __shared__ char smem[];
  short* oc   = (short*)(smem + K2_OC_OFF);    // [64][296] bf16
  float* dsum = (float*)(smem + K2_DS_OFF);    // [64][65] f32
  short* atb  = (short*)(smem + K2_AT_OFF);    // 8 x [16][68] bf16

  const int tid  = threadIdx.x;
  const int lane = tid & 63;
  const int h    = tid >> 6;        // wave id == head id, 0..7
  const int m    = lane & 15;
  const int q    = lane >> 4;
  const int q8   = q * 8;
  const int widx = blockIdx.x;
  const int win  = win0 + widx;

  // phase 0: zero dsum + oc pad cols 256..287
  for (int i = tid; i < 64 * DS_STRIDE; i += 512) dsum[i] = 0.f;
  {
    int r = tid >> 3, c0 = 256 + (tid & 7) * 4;
    s16x4 z = {0, 0, 0, 0};
    *(s16x4*)&oc[r * OC_STRIDE + c0] = z;
  }
  __syncthreads();   // B1

  const short* qpw = qp + (size_t)widx * 16384 + 32 * h + q8;
  const short* kpw = kp + (size_t)widx * 16384 + 32 * h + q8;
  const short* vw  = vp + (size_t)widx * 16384 + (size_t)(4 * h) * 512 + lane * 8;
  const float* dpw = dp + (size_t)widx * 192;

  bf16x8 bk[4];
#pragma unroll
  for (int nt = 0; nt < 4; ++nt) bk[nt] = *(const bf16x8*)&kpw[(16 * nt + m) * 256];
  float kd_c[4];
#pragma unroll
  for (int nt = 0; nt < 4; ++nt) kd_c[nt] = dpw[64 + 16 * nt + m];

  short* atw = atb + h * (16 * AT_STRIDE);

#pragma unroll
  for (int mh = 0; mh < 2; ++mh) {
    bf16x8 aq0 = *(const bf16x8*)&qpw[(16 * (2 * mh + 0) + m) * 256];
    bf16x8 aq1 = *(const bf16x8*)&qpw[(16 * (2 * mh + 1) + m) * 256];
    f32x4 sv[2][4];
#pragma unroll
    for (int nt = 0; nt < 4; ++nt) {
      f32x4 z = {0.f, 0.f, 0.f, 0.f};
      sv[0][nt] = mfma16(aq0, bk[nt], z);
      sv[1][nt] = mfma16(aq1, bk[nt], z);
    }
#pragma unroll
    for (int mt2 = 0; mt2 < 2; ++mt2) {
      const int mt = 2 * mh + mt2;
      float qd_r[4];
#pragma unroll
      for (int r = 0; r < 4; ++r) qd_r[r] = dpw[16 * mt + 4 * q + r];

      float sm[4][4], mx[4], sum[4];
#pragma unroll
      for (int r = 0; r < 4; ++r) mx[r] = -3.4e38f;
#pragma unroll
      for (int nt = 0; nt < 4; ++nt)
#pragma unroll
        for (int r = 0; r < 4; ++r) {
          float tg = qd_r[r] * kd_c[nt];
          float g = 1.f / (1.f + __expf(-tg));
          float s = sv[mt2][nt][r] * g;
          sm[nt][r] = s;
          mx[r] = fmaxf(mx[r], s);
        }
      // head-sum for attn_d
#pragma unroll
      for (int nt = 0; nt < 4; ++nt)
#pragma unroll
        for (int r = 0; r < 4; ++r)
          atomicAdd(&dsum[(16 * mt + 4 * q + r) * DS_STRIDE + 16 * nt + m], sm[nt][r]);
      // row softmax (rows spread over m-lanes within 16-groups)
#pragma unroll
      for (int r = 0; r < 4; ++r) {
#pragma unroll
        for (int msk = 1; msk < 16; msk <<= 1)
          mx[r] = fmaxf(mx[r], __shfl_xor(mx[r], msk));
        sum[r] = 0.f;
      }
#pragma unroll
      for (int nt = 0; nt < 4; ++nt)
#pragma unroll
        for (int r = 0; r < 4; ++r) {
          float p = __expf(sm[nt][r] - mx[r]);
          sm[nt][r] = p;
          sum[r] += p;
        }
#pragma unroll
      for (int r = 0; r < 4; ++r) {
#pragma unroll
        for (int msk = 1; msk < 16; msk <<= 1)
          sum[r] += __shfl_xor(sum[r], msk);
        sum[r] = 1.f / sum[r];
      }
#pragma unroll
      for (int nt = 0; nt < 4; ++nt)
#pragma unroll
        for (int r = 0; r < 4; ++r)
          atw[(4 * q + r) * AT_STRIDE + 16 * nt + m] = f2b(sm[nt][r] * sum[r]);

      // wave-private C->A transpose round trip
      s16x4 l0 = *(const s16x4*)&atw[m * AT_STRIDE + q8];
      s16x4 l1 = *(const s16x4*)&atw[m * AT_STRIDE + q8 + 4];
      s16x4 l2 = *(const s16x4*)&atw[m * AT_STRIDE + 32 + q8];
      s16x4 l3 = *(const s16x4*)&atw[m * AT_STRIDE + 32 + q8 + 4];
      bf16x8 a0, a1;
#pragma unroll
      for (int j = 0; j < 4; ++j) { a0[j] = l0[j]; a0[4 + j] = l1[j]; a1[j] = l2[j]; a1[4 + j] = l3[j]; }

#pragma unroll
      for (int ntv = 0; ntv < 2; ++ntv) {
        bf16x8 bv0 = *(const bf16x8*)&vw[(2 * ntv + 0) * 512];
        bf16x8 bv1 = *(const bf16x8*)&vw[(2 * ntv + 1) * 512];
        f32x4 o = {0.f, 0.f, 0.f, 0.f};
        o = mfma16(a0, bv0, o);
        o = mfma16(a1, bv1, o);
#pragma unroll
        for (int r = 0; r < 4; ++r)
          oc[(16 * mt + 4 * q + r) * OC_STRIDE + 32 * h + 16 * ntv + m] = f2b(o[r]);
      }
    }
  }
  __syncthreads();   // B2: dsum complete

  // attn_d softmax + out_d; wave h owns rows 8h..8h+7, lane&7 = col-chunk
  {
    int row = 8 * h + (lane >> 3);
    int c0 = (lane & 7) * 8;
    float sd[8], vd[8];
#pragma unroll
    for (int j = 0; j < 8; ++j) sd[j] = dsum[row * DS_STRIDE + c0 + j];
#pragma unroll
    for (int j = 0; j < 8; ++j) vd[j] = dpw[128 + c0 + j];
    float mx = sd[0];
#pragma unroll
    for (int j = 1; j < 8; ++j) mx = fmaxf(mx, sd[j]);
#pragma unroll
    for (int msk = 1; msk < 8; msk <<= 1) mx = fmaxf(mx, __shfl_xor(mx, msk));
    float sum = 0.f, ov = 0.f;
#pragma unroll
    for (int j = 0; j < 8; ++j) {
      float e = __expf(sd[j] - mx);
      sum += e;
      ov += e * vd[j];
    }
#pragma unroll
    for (int msk = 1; msk < 8; msk <<= 1) { sum += __shfl_xor(sum, msk); ov += __shfl_xor(ov, msk); }
    if ((lane & 7) == 0) oc[row * OC_STRIDE + 256] = f2b(ov / sum);
  }
  __syncthreads();   // B3: oc complete

  // GEMM2: out = oc[64x288] @ Wout[288x272]; tasks (nt, mhalf): idx = h + 8s, idx<34.
  {
    f32x4 acc2[5][2];
#pragma unroll
    for (int s = 0; s < 5; ++s) {
      acc2[s][0] = f32x4{0.f, 0.f, 0.f, 0.f};
      acc2[s][1] = f32x4{0.f, 0.f, 0.f, 0.f};
    }
    for (int kt = 0; kt < KT; ++kt) {
      bf16x8 ao[4];
#pragma unroll
      for (int mt = 0; mt < 4; ++mt)
        ao[mt] = *(const bf16x8*)&oc[(16 * mt + m) * OC_STRIDE + 32 * kt + q8];
#pragma unroll
      for (int s = 0; s < 5; ++s) {
        int idx = h + 8 * s;
        if (idx < 34) {
          int nt = idx >> 1, mhh = idx & 1;
          bf16x8 bw = *(const bf16x8*)(woutp + ((size_t)(kt * NT_OUT + nt) * 64 + lane) * 8);
          acc2[s][0] = mfma16(ao[2 * mhh + 0], bw, acc2[s][0]);
          acc2[s][1] = mfma16(ao[2 * mhh + 1], bw, acc2[s][1]);
        }
      }
    }
#pragma unroll
    for (int s = 0; s < 5; ++s) {
      int idx = h + 8 * s;
      if (idx >= 34) continue;
      int nt = idx >> 1, mhh = idx & 1;
      int n = 16 * nt + m;
      if (n < D1) {
#pragma unroll
        for (int p = 0; p < 2; ++p) {
          int mt = 2 * mhh + p;
#pragma unroll
          for (int r = 0; r < 4; ++r)
            out[((size_t)win * NTOK + 16 * mt + 4 * q + r) * D1 + n] = acc2[s][p][r];
        }
      }
    }
  }
}

// ======================= fused fallback (R2, verbatim) =======================
__global__ __launch_bounds__(1024)
void vda_attn(const float* __restrict__ x, const short* __restrict__ wcatp,
              const short* __restrict__ woutp, float* __restrict__ out) {
  extern __shared__ char smem[];
  short* xs  = (short*)(smem + XS_OFF);
  short* qs  = (short*)(smem + QS_OFF);
  short* ks  = (short*)(smem + KS_OFF);
  short* vs  = (short*)(smem + VS_OFF);
  float* dsum = (float*)(smem + DS_OFF);
  float* qd_s = (float*)(smem + QD_OFF);
  float* kd_s = (float*)(smem + KD_OFF);
  float* vd_s = (float*)(smem + VD_OFF);
  short* oc = xs;

  const int tid  = threadIdx.x;
  const int lane = tid & 63;
  const int w    = tid >> 6;
  const int m    = lane & 15;
  const int q    = lane >> 4;
  const int q8   = q * 8;
  const int win  = blockIdx.x;

  for (int i = tid; i < 64 * 39; i += 1024) {
    int r = i / 39, c = 257 + (i % 39);
    xs[r * XS_STRIDE + c] = 0;
  }
  for (int i = tid; i < 64 * DS_STRIDE; i += 1024) dsum[i] = 0.f;
  {
    const float4* xw4 = (const float4*)(x + (size_t)win * (NTOK * D1));
    for (int f4 = tid; f4 < 4112; f4 += 1024) {
      float4 v = xw4[f4];
      float vals[4] = {v.x, v.y, v.z, v.w};
      int o0 = f4 * 4;
      int r0 = o0 / D1, c0 = o0 - r0 * D1;
#pragma unroll
      for (int jj = 0; jj < 4; ++jj) {
        int c = c0 + jj, r = r0;
        if (c >= D1) { c -= D1; r += 1; }
        xs[r * XS_STRIDE + c] = f2b(vals[jj]);
      }
    }
  }
  __syncthreads();

  {
    f32x4 acc[4][4];
#pragma unroll
    for (int t = 0; t < 4; ++t)
#pragma unroll
      for (int mt = 0; mt < 4; ++mt) acc[t][mt] = f32x4{0.f, 0.f, 0.f, 0.f};

    for (int kt = 0; kt < KT; ++kt) {
      bf16x8 af[4];
#pragma unroll
      for (int mt = 0; mt < 4; ++mt)
        af[mt] = *(const bf16x8*)&xs[(16 * mt + m) * XS_STRIDE + 32 * kt + q8];
#pragma unroll
      for (int t = 0; t < 4; ++t) {
        int nt = w + 16 * t;
        if (nt < NT_CAT) {
          bf16x8 bfr = *(const bf16x8*)(wcatp + ((size_t)(kt * NT_CAT + nt) * 64 + lane) * 8);
#pragma unroll
          for (int mt = 0; mt < 4; ++mt)
            acc[t][mt] = mfma16(af[mt], bfr, acc[t][mt]);
        }
      }
    }
#pragma unroll
    for (int t = 0; t < 4; ++t) {
      int nt = w + 16 * t;
      if (nt >= NT_CAT) continue;
      int c = nt * 16 + m;
      if (c < 256) {
#pragma unroll
        for (int mt = 0; mt < 4; ++mt)
#pragma unroll
          for (int r = 0; r < 4; ++r)
            qs[(16 * mt + 4 * q + r) * QK_STRIDE + c] = f2b(acc[t][mt][r]);
      } else if (c < 512) {
#pragma unroll
        for (int mt = 0; mt < 4; ++mt)
#pragma unroll
          for (int r = 0; r < 4; ++r)
            ks[(16 * mt + 4 * q + r) * QK_STRIDE + (c - 256)] = f2b(acc[t][mt][r]);
      } else if (c < 768) {
#pragma unroll
        for (int mt = 0; mt < 4; ++mt) {
          int frag = (nt - 32) * 2 + (mt >> 1);
          int q2 = (2 * mt + (q >> 1)) & 3;
          int j0 = 4 * (q & 1);
          s16x4 pk;
#pragma unroll
          for (int r = 0; r < 4; ++r) pk[r] = f2b(acc[t][mt][r]);
          *(s16x4*)&vs[frag * 512 + (q2 * 16 + m) * 8 + j0] = pk;
        }
      } else {
        if (m < 3) {
          float* dst = (m == 0) ? qd_s : (m == 1) ? kd_s : vd_s;
#pragma unroll
          for (int mt = 0; mt < 4; ++mt)
#pragma unroll
            for (int r = 0; r < 4; ++r)
              dst[16 * mt + 4 * q + r] = acc[t][mt][r];
        }
      }
    }
  }
  __syncthreads();

  const int rw = w & 3;
  const int hp = w >> 2;

  bf16x8 aq[2];
#pragma unroll
  for (int hh = 0; hh < 2; ++hh)
    aq[hh] = *(const bf16x8*)&qs[(16 * rw + m) * QK_STRIDE + 32 * (2 * hp + hh) + q8];

  float gate[4][4], ssum[4][4];
  {
    float qd_r[4], kd_c[4];
#pragma unroll
    for (int r = 0; r < 4; ++r) qd_r[r] = qd_s[16 * rw + 4 * q + r];
#pragma unroll
    for (int nt = 0; nt < 4; ++nt) kd_c[nt] = kd_s[16 * nt + m];
#pragma unroll
    for (int nt = 0; nt < 4; ++nt)
#pragma unroll
      for (int r = 0; r < 4; ++r) {
        float t = qd_r[r] * kd_c[nt];
        gate[nt][r] = 1.f / (1.f + __expf(-t));
        ssum[nt][r] = 0.f;
      }
  }
  __syncthreads();

  if (hp == 0) {
    bf16x8 z = {0, 0, 0, 0, 0, 0, 0, 0};
    *(bf16x8*)&oc[(16 * rw + m) * OC_STRIDE + 256 + q8] = z;
  }

  short* atw = (short*)(smem + QS_OFF) + w * (16 * AT_STRIDE);

#pragma unroll
  for (int hh = 0; hh < 2; ++hh) {
    int h = 2 * hp + hh;
    f32x4 sv[4];
#pragma unroll
    for (int nt = 0; nt < 4; ++nt) {
      bf16x8 bkf = *(const bf16x8*)&ks[(16 * nt + m) * QK_STRIDE + 32 * h + q8];
      f32x4 z = {0.f, 0.f, 0.f, 0.f};
      sv[nt] = mfma16(aq[hh], bkf, z);
    }
    float sm[4][4], mx[4], sum[4];
#pragma unroll
    for (int r = 0; r < 4; ++r) mx[r] = -3.4e38f;
#pragma unroll
    for (int nt = 0; nt < 4; ++nt)
#pragma unroll
      for (int r = 0; r < 4; ++r) {
        float s = sv[nt][r] * gate[nt][r];
        ssum[nt][r] += s;
        sm[nt][r] = s;
        mx[r] = fmaxf(mx[r], s);
      }
#pragma unroll
    for (int r = 0; r < 4; ++r) {
#pragma unroll
      for (int msk = 1; msk < 16; msk <<= 1)
        mx[r] = fmaxf(mx[r], __shfl_xor(mx[r], msk));
      sum[r] = 0.f;
    }
#pragma unroll
    for (int nt = 0; nt < 4; ++nt)
#pragma unroll
      for (int r = 0; r < 4; ++r) {
        float p = __expf(sm[nt][r] - mx[r]);
        sm[nt][r] = p;
        sum[r] += p;
      }
#pragma unroll
    for (int r = 0; r < 4; ++r) {
#pragma unroll
      for (int msk = 1; msk < 16; msk <<= 1)
        sum[r] += __shfl_xor(sum[r], msk);
      sum[r] = 1.f / sum[r];
    }
#pragma unroll
    for (int nt = 0; nt < 4; ++nt)
#pragma unroll
      for (int r = 0; r < 4; ++r)
        atw[(4 * q + r) * AT_STRIDE + 16 * nt + m] = f2b(sm[nt][r] * sum[r]);

    s16x4 l0 = *(const s16x4*)&atw[m * AT_STRIDE + q8];
    s16x4 l1 = *(const s16x4*)&atw[m * AT_STRIDE + q8 + 4];
    s16x4 l2 = *(const s16x4*)&atw[m * AT_STRIDE + 32 + q8];
    s16x4 l3 = *(const s16x4*)&atw[m * AT_STRIDE + 32 + q8 + 4];
    bf16x8 a0, a1;
#pragma unroll
    for (int j = 0; j < 4; ++j) { a0[j] = l0[j]; a0[4 + j] = l1[j]; a1[j] = l2[j]; a1[4 + j] = l3[j]; }

#pragma unroll
    for (int ntp = 0; ntp < 2; ++ntp) {
      bf16x8 bv0 = *(const bf16x8*)&vs[(((2 * h + ntp) * 2) + 0) * 512 + lane * 8];
      bf16x8 bv1 = *(const bf16x8*)&vs[(((2 * h + ntp) * 2) + 1) * 512 + lane * 8];
      f32x4 o = {0.f, 0.f, 0.f, 0.f};
      o = mfma16(a0, bv0, o);
      o = mfma16(a1, bv1, o);
#pragma unroll
      for (int r = 0; r < 4; ++r)
        oc[(16 * rw + 4 * q + r) * OC_STRIDE + 32 * h + 16 * ntp + m] = f2b(o[r]);
    }
  }

#pragma unroll
  for (int nt = 0; nt < 4; ++nt)
#pragma unroll
    for (int r = 0; r < 4; ++r)
      atomicAdd(&dsum[(16 * rw + 4 * q + r) * DS_STRIDE + 16 * nt + m], ssum[nt][r]);
  __syncthreads();

  if (hp == 0) {
    float sd[4][4], mx[4], sum[4];
#pragma unroll
    for (int nt = 0; nt < 4; ++nt)
#pragma unroll
      for (int r = 0; r < 4; ++r)
        sd[nt][r] = dsum[(16 * rw + 4 * q + r) * DS_STRIDE + 16 * nt + m];
#pragma unroll
    for (int r = 0; r < 4; ++r) mx[r] = -3.4e38f;
#pragma unroll
    for (int nt = 0; nt < 4; ++nt)
#pragma unroll
      for (int r = 0; r < 4; ++r) mx[r] = fmaxf(mx[r], sd[nt][r]);
#pragma unroll
    for (int r = 0; r < 4; ++r) {
#pragma unroll
      for (int msk = 1; msk < 16; msk <<= 1)
        mx[r] = fmaxf(mx[r], __shfl_xor(mx[r], msk));
      sum[r] = 0.f;
    }
#pragma unroll
    for (int nt = 0; nt < 4; ++nt)
#pragma unroll
      for (int r = 0; r < 4; ++r) {
        sd[nt][r] = __expf(sd[nt][r] - mx[r]);
        sum[r] += sd[nt][r];
      }
#pragma unroll
    for (int r = 0; r < 4; ++r) {
#pragma unroll
      for (int msk = 1; msk < 16; msk <<= 1)
        sum[r] += __shfl_xor(sum[r], msk);
      sum[r] = 1.f / sum[r];
    }
    float vd_c[4];
#pragma unroll
    for (int nt = 0; nt < 4; ++nt) vd_c[nt] = vd_s[16 * nt + m];
    float ov[4] = {0.f, 0.f, 0.f, 0.f};
#pragma unroll
    for (int nt = 0; nt < 4; ++nt)
#pragma unroll
      for (int r = 0; r < 4; ++r) ov[r] += sd[nt][r] * vd_c[nt];
#pragma unroll
    for (int r = 0; r < 4; ++r) {
#pragma unroll
      for (int msk = 1; msk < 16; msk <<= 1)
        ov[r] += __shfl_xor(ov[r], msk);
    }
    if (m == 0) {
#pragma unroll
      for (int r = 0; r < 4; ++r)
        oc[(16 * rw + 4 * q + r) * OC_STRIDE + 256] = f2b(ov[r] * sum[r]);
    }
  }
  __syncthreads();

  {
    f32x4 acc2[2][4];
#pragma unroll
    for (int t = 0; t < 2; ++t)
#pragma unroll
      for (int mt = 0; mt < 4; ++mt) acc2[t][mt] = f32x4{0.f, 0.f, 0.f, 0.f};

    for (int kt = 0; kt < KT; ++kt) {
      bf16x8 ao[4];
#pragma unroll
      for (int mt = 0; mt < 4; ++mt)
        ao[mt] = *(const bf16x8*)&oc[(16 * mt + m) * OC_STRIDE + 32 * kt + q8];
#pragma unroll
      for (int t = 0; t < 2; ++t) {
        int nt = w + 16 * t;
        if (nt < NT_OUT) {
          bf16x8 bw = *(const bf16x8*)(woutp + ((size_t)(kt * NT_OUT + nt) * 64 + lane) * 8);
#pragma unroll
          for (int mt = 0; mt < 4; ++mt)
            acc2[t][mt] = mfma16(ao[mt], bw, acc2[t][mt]);
        }
      }
    }
#pragma unroll
    for (int t = 0; t < 2; ++t) {
      int nt = w + 16 * t;
      if (nt >= NT_OUT) continue;
      int n = 16 * nt + m;
      if (n < D1) {
#pragma unroll
        for (int mt = 0; mt < 4; ++mt)
#pragma unroll
          for (int r = 0; r < 4; ++r)
            out[((size_t)win * NTOK + 16 * mt + 4 * q + r) * D1 + n] = acc2[t][mt][r];
      }
    }
  }
}

extern "C" void kernel_launch(void* const* d_in, const int* in_sizes, int n_in,
                              void* d_out, int out_size, void* d_ws, size_t ws_size,
                              hipStream_t stream) {
  (void)n_in; (void)out_size;
  const float* x    = (const float*)d_in[0];
  const float* Wqv  = (const float*)d_in[1];
  const float* Wkv  = (const float*)d_in[2];
  const float* Wvv  = (const float*)d_in[3];
  const float* Wqd  = (const float*)d_in[4];
  const float* Wkd  = (const float*)d_in[5];
  const float* Wvd  = (const float*)d_in[6];
  const float* Wout = (const float*)d_in[7];
  float* out = (float*)d_out;

  short* wcatp = (short*)d_ws;
  short* woutp = wcatp + WCAT_ELEMS;

  int nwin = in_sizes[0] / (NTOK * D1);         // 2048

  int prep_blocks = (WCAT_ELEMS + WOUT_ELEMS) / 256;   // 1188, exact
  prep_weights<<<prep_blocks, 256, 0, stream>>>(Wqv, Wkv, Wvv, Wqd, Wkd, Wvd, Wout, wcatp, woutp);

  // chunked split path: per window 99,072 B (qp 32K + kp 32K + vp 32K + dp 768)
  const size_t woff = (size_t)(WCAT_ELEMS + WOUT_ELEMS) * 2;   // 608,256 (256-aligned)
  const size_t per_win = 99072;
  size_t avail = (ws_size > woff) ? ws_size - woff : 0;
  long long cwll = (long long)(avail / per_win);
  int cw = (cwll > nwin) ? nwin : (int)cwll;

  if (cw < 64) {
    // workspace too small -> R2 fused fallback
    hipFuncSetAttribute((const void*)vda_attn, hipFuncAttributeMaxDynamicSharedMemorySize, LDS_SIZE);
    vda_attn<<<nwin, 1024, LDS_SIZE, stream>>>(x, wcatp, woutp, out);
    return;
  }

  hipFuncSetAttribute((const void*)vda_k2, hipFuncAttributeMaxDynamicSharedMemorySize, K2_LDS);

  char* pbase = (char*)d_ws + woff;
  short* qp = (short*)pbase;
  short* kp = qp + (size_t)cw * 16384;
  short* vp = kp + (size_t)cw * 16384;
  float* dpf = (float*)(vp + (size_t)cw * 16384);

  for (int base = 0; base < nwin; base += cw) {
    int g = nwin - base;
    if (g > cw) g = cw;
    vda_k1<<<g, 1024, 0, stream>>>(x, wcatp, qp, kp, vp, dpf, base);
    vda_k2<<<g, 512, K2_LDS, stream>>>(qp, kp, vp, dpf, woutp, out, base);
  }
}

// Round 2
// 619.486 us; speedup vs baseline: 1.3211x; 1.3211x over previous
//
#include <hip/hip_runtime.h>

// VisualDepthAttention on MI355X (gfx950) — round 4.
// R3 post-mortem: split kernels REGRESSED (818 us; k2 alone 550 us, MfmaUtil 2.2%,
// VALU 59%): wave=head serialized 4x more softmax per wave + gate recompute + global
// qkv round-trip at the dependency head. Reverted to R2 fused structure.
// R4 changes vs R2 (both evidence-driven from R2 counters):
//  (1) Fragment-linear LDS layouts for xs/oc, qs, ks (vs was already frag-linear).
//      R2's row-major strides gave 8-way bank conflicts on EVERY b128 GEMM read
//      (12.9M conflict cycles/dispatch). Frag-linear reads are lane-linear 16B ->
//      conflict-free.
//  (2) x pre-pass: x fp32 -> bf16 in A-frag-linear window layout (ws, 75.5MB,
//      chunked; R2-fused fallback if ws too small). Main-kernel staging becomes a
//      pure int4 copy (no f2b, no div/mod), x HBM read halves (131->75.5MB).
// Kept identical: attention math, dsum atomics, at-scratch transpose, barrier count.

#define D1    257
#define NTOK  64
#define KT    9      // K padded to 288 = 9*32
#define NT_CAT 49    // Wcat N = 784 = 49*16
#define NT_OUT 17    // Wout N = 272 = 17*16
#define SCALE 0.17677669529663687f

// ---- R4 fused kernel LDS layout (frag-linear). Total 154,624 <= 163,840 ----
#define XS2_OFF 0          // xs/oc: 36 frags x 1KB = 36,864 (frag = kt*4+mt)
#define QS2_OFF 36864      // qs: 32 frags x 1KB = 32,768 (frag = colblk*4+rowblk); at overlay 34,816
#define KS2_OFF 71680      // ks: 32 frags = 32,768
#define VS2_OFF 104448     // vs: 32 frags = 32,768 (B-frag-linear, as R2)
#define DS2_OFF 137216     // dsum fp32 [64][65] = 16,640
#define QD2_OFF 153856
#define KD2_OFF 154112
#define VD2_OFF 154368
#define LDS2    154624
#define AT_STRIDE 68
#define DS_STRIDE 65

// ---- R2 fallback LDS layout (verbatim) ----
#define XS_OFF    0
#define XS_STRIDE 296
#define OC_STRIDE 296
#define QS_OFF    37888
#define QK_STRIDE 264
#define KS_OFF    72704
#define VS_OFF    106496
#define DS_OFF    139264
#define QD_OFF    155904
#define KD_OFF    156160
#define VD_OFF    156416
#define LDS_SIZE  156672

#define WCAT_ELEMS (KT * NT_CAT * 512)   // 225792 bf16
#define WOUT_ELEMS (KT * NT_OUT * 512)   // 78336 bf16
#define XWIN_ELEMS (36 * 512)            // 18432 bf16 per window (frag-linear)

using bf16x8 = __attribute__((ext_vector_type(8))) short;
using s16x4  = __attribute__((ext_vector_type(4))) short;
using f32x4  = __attribute__((ext_vector_type(4))) float;

__device__ __forceinline__ short f2b(float f) {
  unsigned u = __float_as_uint(f);
  u = (u + 0x7FFFu + ((u >> 16) & 1u)) >> 16;   // RNE
  return (short)u;
}

__device__ __forceinline__ f32x4 mfma16(bf16x8 a, bf16x8 b, f32x4 c) {
  return __builtin_amdgcn_mfma_f32_16x16x32_bf16(a, b, c, 0, 0, 0);
}

__global__ void prep_weights(const float* __restrict__ Wqv, const float* __restrict__ Wkv,
                             const float* __restrict__ Wvv, const float* __restrict__ Wqd,
                             const float* __restrict__ Wkd, const float* __restrict__ Wvd,
                             const float* __restrict__ Wout,
                             short* __restrict__ wcatp, short* __restrict__ woutp) {
  int idx = blockIdx.x * 256 + threadIdx.x;
  if (idx < WCAT_ELEMS) {
    int j = idx & 7, lane = (idx >> 3) & 63, rest = idx >> 9;
    int nt = rest % NT_CAT, kt = rest / NT_CAT;
    int k = 32 * kt + (lane >> 4) * 8 + j;
    int n = 16 * nt + (lane & 15);
    float v = 0.f;
    if (k < D1) {
      if (n < 256)       v = Wqv[k * 256 + n] * SCALE;
      else if (n < 512)  v = Wkv[k * 256 + (n - 256)];
      else if (n < 768)  v = Wvv[k * 256 + (n - 512)];
      else if (n == 768) v = Wqd[k] * SCALE;
      else if (n == 769) v = Wkd[k];
      else if (n == 770) v = Wvd[k];
    }
    wcatp[idx] = f2b(v);
  } else {
    int i2 = idx - WCAT_ELEMS;
    int j = i2 & 7, lane = (i2 >> 3) & 63, rest = i2 >> 9;
    int nt = rest % NT_OUT, kt = rest / NT_OUT;
    int k = 32 * kt + (lane >> 4) * 8 + j;
    int n = 16 * nt + (lane & 15);
    float v = (k < D1 && n < D1) ? Wout[k * D1 + n] : 0.f;
    woutp[i2] = f2b(v);
  }
}

// x fp32 -> bf16 A-frag-linear per window. Frag (kt,mt): lane(m=l&15,q=l>>4), j:
// element [row=16mt+m][col=32kt+8q+j]; col>=257 zero-padded.
__global__ void prep_x(const float* __restrict__ x, short* __restrict__ xbf, int win0) {
  int i = blockIdx.x * 256 + threadIdx.x;       // 0..18431
  int widx = blockIdx.y;
  int j = i & 7, lane = (i >> 3) & 63, frag = i >> 9;
  int kt = frag >> 2, mt = frag & 3;
  int m = lane & 15, q = lane >> 4;
  int row = 16 * mt + m;
  int col = 32 * kt + 8 * q + j;
  float v = 0.f;
  if (col < D1)
    v = x[((size_t)(win0 + widx) * NTOK + row) * D1 + col];
  xbf[(size_t)widx * XWIN_ELEMS + i] = f2b(v);
}

// ======================= R4 fused kernel =======================
__global__ __launch_bounds__(1024)
void vda_attn2(const short* __restrict__ xbf, const short* __restrict__ wcatp,
               const short* __restrict__ woutp, float* __restrict__ out, int win0) {
  extern __shared__ char smem[];
  short* xs   = (short*)(smem + XS2_OFF);
  short* qs   = (short*)(smem + QS2_OFF);
  short* ks   = (short*)(smem + KS2_OFF);
  short* vs   = (short*)(smem + VS2_OFF);
  float* dsum = (float*)(smem + DS2_OFF);
  float* qd_s = (float*)(smem + QD2_OFF);
  float* kd_s = (float*)(smem + KD2_OFF);
  float* vd_s = (float*)(smem + VD2_OFF);
  short* oc = xs;

  const int tid  = threadIdx.x;
  const int lane = tid & 63;
  const int w    = tid >> 6;        // wave 0..15
  const int m    = lane & 15;
  const int q    = lane >> 4;
  const int q8   = q * 8;
  const int widx = blockIdx.x;
  const int win  = win0 + widx;

  // ---- Phase A: pure copy of pre-converted frag-linear x + zero dsum.
  for (int i = tid; i < 64 * DS_STRIDE; i += 1024) dsum[i] = 0.f;
  {
    const int4* src = (const int4*)(xbf + (size_t)widx * XWIN_ELEMS);
    int4* dst = (int4*)xs;
    for (int i = tid; i < 2304; i += 1024) dst[i] = src[i];   // 36,864 B
  }
  __syncthreads();   // S1

  // ---- Phase B: C = xs[64x288] @ Wcat[288x784]. kt-outer, acc resident.
  // Wave w owns nt in {w, w+16, w+32, w+48}. A-reads lane-linear (conflict-free).
  {
    f32x4 acc[4][4];
#pragma unroll
    for (int t = 0; t < 4; ++t)
#pragma unroll
      for (int mt = 0; mt < 4; ++mt) acc[t][mt] = f32x4{0.f, 0.f, 0.f, 0.f};

    for (int kt = 0; kt < KT; ++kt) {
      bf16x8 af[4];
#pragma unroll
      for (int mt = 0; mt < 4; ++mt)
        af[mt] = *(const bf16x8*)&xs[(kt * 4 + mt) * 512 + lane * 8];
#pragma unroll
      for (int t = 0; t < 4; ++t) {
        int nt = w + 16 * t;
        if (nt < NT_CAT) {
          bf16x8 bfr = *(const bf16x8*)(wcatp + ((size_t)(kt * NT_CAT + nt) * 64 + lane) * 8);
#pragma unroll
          for (int mt = 0; mt < 4; ++mt)
            acc[t][mt] = mfma16(af[mt], bfr, acc[t][mt]);
        }
      }
    }
    // epilogue: t=0 -> Q, t=1 -> K, t=2 -> V, t=3 -> depth (w==0 only).
    // Q/K frag-linear: element (row,col) -> frag (col>>5)*4+(row>>4),
    //   slot (((col>>3)&3)*16 + (row&15))*8 + (col&7).
    {
      // t = 0: Q cols c = 16*w + m
      int cq = (2 * w + (m >> 3)) & 3;
      int jj = m & 7;
      int fb = (w >> 1) * 4;
#pragma unroll
      for (int mt = 0; mt < 4; ++mt)
#pragma unroll
        for (int r = 0; r < 4; ++r)
          qs[(fb + mt) * 512 + (cq * 16 + 4 * q + r) * 8 + jj] = f2b(acc[0][mt][r]);
      // t = 1: K cols c-256 = 16*w + m (same frag math)
#pragma unroll
      for (int mt = 0; mt < 4; ++mt)
#pragma unroll
        for (int r = 0; r < 4; ++r)
          ks[(fb + mt) * 512 + (cq * 16 + 4 * q + r) * 8 + jj] = f2b(acc[1][mt][r]);
      // t = 2: V B-frag-linear (R2-proven layout), ntv = w
#pragma unroll
      for (int mt = 0; mt < 4; ++mt) {
        int frag = w * 2 + (mt >> 1);
        int q2 = (2 * mt + (q >> 1)) & 3;
        int j0 = 4 * (q & 1);
        s16x4 pk;
#pragma unroll
        for (int r = 0; r < 4; ++r) pk[r] = f2b(acc[2][mt][r]);
        *(s16x4*)&vs[frag * 512 + (q2 * 16 + m) * 8 + j0] = pk;
      }
      // t = 3: nt = w+48, only w==0 valid -> depth cols 768..770
      if (w == 0 && m < 3) {
        float* dst = (m == 0) ? qd_s : (m == 1) ? kd_s : vd_s;
#pragma unroll
        for (int mt = 0; mt < 4; ++mt)
#pragma unroll
          for (int r = 0; r < 4; ++r)
            dst[16 * mt + 4 * q + r] = acc[3][mt][r];
      }
    }
  }
  __syncthreads();   // S2

  // ---- Phase C: wave = (rw = w&3 row tile, hp = w>>2 head pair {2hp, 2hp+1}).
  const int rw = w & 3;
  const int hp = w >> 2;

  bf16x8 aq[2];
#pragma unroll
  for (int hh = 0; hh < 2; ++hh)
    aq[hh] = *(const bf16x8*)&qs[(((2 * hp + hh) * 4 + rw)) * 512 + lane * 8];

  float gate[4][4], ssum[4][4];
  {
    float qd_r[4], kd_c[4];
#pragma unroll
    for (int r = 0; r < 4; ++r) qd_r[r] = qd_s[16 * rw + 4 * q + r];
#pragma unroll
    for (int nt = 0; nt < 4; ++nt) kd_c[nt] = kd_s[16 * nt + m];
#pragma unroll
    for (int nt = 0; nt < 4; ++nt)
#pragma unroll
      for (int r = 0; r < 4; ++r) {
        float t = qd_r[r] * kd_c[nt];
        gate[nt][r] = 1.f / (1.f + __expf(-t));
        ssum[nt][r] = 0.f;
      }
  }
  __syncthreads();   // S3 (qs dead -> at overlay live; oc (over xs) writable)

  if (hp == 0) {     // zero oc pad frags 32..35 (cols 256..287)
    int4 z4; z4.x = 0; z4.y = 0; z4.z = 0; z4.w = 0;
    ((int4*)(oc + 32 * 512))[rw * 64 + lane] = z4;
  }

  short* atw = (short*)(smem + QS2_OFF) + w * (16 * AT_STRIDE);

#pragma unroll
  for (int hh = 0; hh < 2; ++hh) {
    int h = 2 * hp + hh;
    f32x4 sv[4];
#pragma unroll
    for (int nt = 0; nt < 4; ++nt) {
      bf16x8 bk = *(const bf16x8*)&ks[(h * 4 + nt) * 512 + lane * 8];
      f32x4 z = {0.f, 0.f, 0.f, 0.f};
      sv[nt] = mfma16(aq[hh], bk, z);
    }
    float sm[4][4], mx[4], sum[4];
#pragma unroll
    for (int r = 0; r < 4; ++r) mx[r] = -3.4e38f;
#pragma unroll
    for (int nt = 0; nt < 4; ++nt)
#pragma unroll
      for (int r = 0; r < 4; ++r) {
        float s = sv[nt][r] * gate[nt][r];
        ssum[nt][r] += s;
        sm[nt][r] = s;
        mx[r] = fmaxf(mx[r], s);
      }
#pragma unroll
    for (int r = 0; r < 4; ++r) {
#pragma unroll
      for (int msk = 1; msk < 16; msk <<= 1)
        mx[r] = fmaxf(mx[r], __shfl_xor(mx[r], msk));
      sum[r] = 0.f;
    }
#pragma unroll
    for (int nt = 0; nt < 4; ++nt)
#pragma unroll
      for (int r = 0; r < 4; ++r) {
        float p = __expf(sm[nt][r] - mx[r]);
        sm[nt][r] = p;
        sum[r] += p;
      }
#pragma unroll
    for (int r = 0; r < 4; ++r) {
#pragma unroll
      for (int msk = 1; msk < 16; msk <<= 1)
        sum[r] += __shfl_xor(sum[r], msk);
      sum[r] = 1.f / sum[r];
    }
#pragma unroll
    for (int nt = 0; nt < 4; ++nt)
#pragma unroll
      for (int r = 0; r < 4; ++r)
        atw[(4 * q + r) * AT_STRIDE + 16 * nt + m] = f2b(sm[nt][r] * sum[r]);

    // A-frags of attn (wave-private LDS round trip)
    s16x4 l0 = *(const s16x4*)&atw[m * AT_STRIDE + q8];
    s16x4 l1 = *(const s16x4*)&atw[m * AT_STRIDE + q8 + 4];
    s16x4 l2 = *(const s16x4*)&atw[m * AT_STRIDE + 32 + q8];
    s16x4 l3 = *(const s16x4*)&atw[m * AT_STRIDE + 32 + q8 + 4];
    bf16x8 a0, a1;
#pragma unroll
    for (int j = 0; j < 4; ++j) { a0[j] = l0[j]; a0[4 + j] = l1[j]; a1[j] = l2[j]; a1[4 + j] = l3[j]; }

#pragma unroll
    for (int ntv = 0; ntv < 2; ++ntv) {
      bf16x8 bv0 = *(const bf16x8*)&vs[(((2 * h + ntv) * 2) + 0) * 512 + lane * 8];
      bf16x8 bv1 = *(const bf16x8*)&vs[(((2 * h + ntv) * 2) + 1) * 512 + lane * 8];
      f32x4 o = {0.f, 0.f, 0.f, 0.f};
      o = mfma16(a0, bv0, o);
      o = mfma16(a1, bv1, o);
      // oc frag-linear write: row=16rw+4q+r, col=32h+16ntv+m
      int cq2 = (2 * ntv + (m >> 3)) & 3;
#pragma unroll
      for (int r = 0; r < 4; ++r)
        oc[(h * 4 + rw) * 512 + (cq2 * 16 + 4 * q + r) * 8 + (m & 7)] = f2b(o[r]);
    }
  }

  // head-sum reduction across the 4 hp-waves sharing rw
#pragma unroll
  for (int nt = 0; nt < 4; ++nt)
#pragma unroll
    for (int r = 0; r < 4; ++r)
      atomicAdd(&dsum[(16 * rw + 4 * q + r) * DS_STRIDE + 16 * nt + m], ssum[nt][r]);
  __syncthreads();   // S5

  if (hp == 0) {     // attn_d softmax + out_d for rows 16rw..16rw+15
    float sd[4][4], mx[4], sum[4];
#pragma unroll
    for (int nt = 0; nt < 4; ++nt)
#pragma unroll
      for (int r = 0; r < 4; ++r)
        sd[nt][r] = dsum[(16 * rw + 4 * q + r) * DS_STRIDE + 16 * nt + m];
#pragma unroll
    for (int r = 0; r < 4; ++r) mx[r] = -3.4e38f;
#pragma unroll
    for (int nt = 0; nt < 4; ++nt)
#pragma unroll
      for (int r = 0; r < 4; ++r) mx[r] = fmaxf(mx[r], sd[nt][r]);
#pragma unroll
    for (int r = 0; r < 4; ++r) {
#pragma unroll
      for (int msk = 1; msk < 16; msk <<= 1)
        mx[r] = fmaxf(mx[r], __shfl_xor(mx[r], msk));
      sum[r] = 0.f;
    }
#pragma unroll
    for (int nt = 0; nt < 4; ++nt)
#pragma unroll
      for (int r = 0; r < 4; ++r) {
        sd[nt][r] = __expf(sd[nt][r] - mx[r]);
        sum[r] += sd[nt][r];
      }
#pragma unroll
    for (int r = 0; r < 4; ++r) {
#pragma unroll
      for (int msk = 1; msk < 16; msk <<= 1)
        sum[r] += __shfl_xor(sum[r], msk);
      sum[r] = 1.f / sum[r];
    }
    float vd_c[4];
#pragma unroll
    for (int nt = 0; nt < 4; ++nt) vd_c[nt] = vd_s[16 * nt + m];
    float ov[4] = {0.f, 0.f, 0.f, 0.f};
#pragma unroll
    for (int nt = 0; nt < 4; ++nt)
#pragma unroll
      for (int r = 0; r < 4; ++r) ov[r] += sd[nt][r] * vd_c[nt];
#pragma unroll
    for (int r = 0; r < 4; ++r) {
#pragma unroll
      for (int msk = 1; msk < 16; msk <<= 1)
        ov[r] += __shfl_xor(ov[r], msk);
    }
    if (m == 0) {
      // col 256 -> frag 32+rw, cq=0, j=0
#pragma unroll
      for (int r = 0; r < 4; ++r)
        oc[(32 + rw) * 512 + (4 * q + r) * 8] = f2b(ov[r] * sum[r]);
    }
  }
  __syncthreads();   // S6

  // ---- Phase D: out = oc[64x288] @ Wout[288x272]; wave w owns nt {w, w+16}.
  {
    f32x4 acc2[2][4];
#pragma unroll
    for (int t = 0; t < 2; ++t)
#pragma unroll
      for (int mt = 0; mt < 4; ++mt) acc2[t][mt] = f32x4{0.f, 0.f, 0.f, 0.f};

    for (int kt = 0; kt < KT; ++kt) {
      bf16x8 ao[4];
#pragma unroll
      for (int mt = 0; mt < 4; ++mt)
        ao[mt] = *(const bf16x8*)&oc[(kt * 4 + mt) * 512 + lane * 8];
#pragma unroll
      for (int t = 0; t < 2; ++t) {
        int nt = w + 16 * t;
        if (nt < NT_OUT) {
          bf16x8 bw = *(const bf16x8*)(woutp + ((size_t)(kt * NT_OUT + nt) * 64 + lane) * 8);
#pragma unroll
          for (int mt = 0; mt < 4; ++mt)
            acc2[t][mt] = mfma16(ao[mt], bw, acc2[t][mt]);
        }
      }
    }
#pragma unroll
    for (int t = 0; t < 2; ++t) {
      int nt = w + 16 * t;
      if (nt >= NT_OUT) continue;
      int n = 16 * nt + m;
      if (n < D1) {
#pragma unroll
        for (int mt = 0; mt < 4; ++mt)
#pragma unroll
          for (int r = 0; r < 4; ++r)
            out[((size_t)win * NTOK + 16 * mt + 4 * q + r) * D1 + n] = acc2[t][mt][r];
      }
    }
  }
}

// ======================= R2 fused fallback (verbatim) =======================
__global__ __launch_bounds__(1024)
void vda_attn(const float* __restrict__ x, const short* __restrict__ wcatp,
              const short* __restrict__ woutp, float* __restrict__ out) {
  extern __shared__ char smem[];
  short* xs  = (short*)(smem + XS_OFF);
  short* qs  = (short*)(smem + QS_OFF);
  short* ks  = (short*)(smem + KS_OFF);
  short* vs  = (short*)(smem + VS_OFF);
  float* dsum = (float*)(smem + DS_OFF);
  float* qd_s = (float*)(smem + QD_OFF);
  float* kd_s = (float*)(smem + KD_OFF);
  float* vd_s = (float*)(smem + VD_OFF);
  short* oc = xs;

  const int tid  = threadIdx.x;
  const int lane = tid & 63;
  const int w    = tid >> 6;
  const int m    = lane & 15;
  const int q    = lane >> 4;
  const int q8   = q * 8;
  const int win  = blockIdx.x;

  for (int i = tid; i < 64 * 39; i += 1024) {
    int r = i / 39, c = 257 + (i % 39);
    xs[r * XS_STRIDE + c] = 0;
  }
  for (int i = tid; i < 64 * DS_STRIDE; i += 1024) dsum[i] = 0.f;
  {
    const float4* xw4 = (const float4*)(x + (size_t)win * (NTOK * D1));
    for (int f4 = tid; f4 < 4112; f4 += 1024) {
      float4 v = xw4[f4];
      float vals[4] = {v.x, v.y, v.z, v.w};
      int o0 = f4 * 4;
      int r0 = o0 / D1, c0 = o0 - r0 * D1;
#pragma unroll
      for (int jj = 0; jj < 4; ++jj) {
        int c = c0 + jj, r = r0;
        if (c >= D1) { c -= D1; r += 1; }
        xs[r * XS_STRIDE + c] = f2b(vals[jj]);
      }
    }
  }
  __syncthreads();

  {
    f32x4 acc[4][4];
#pragma unroll
    for (int t = 0; t < 4; ++t)
#pragma unroll
      for (int mt = 0; mt < 4; ++mt) acc[t][mt] = f32x4{0.f, 0.f, 0.f, 0.f};

    for (int kt = 0; kt < KT; ++kt) {
      bf16x8 af[4];
#pragma unroll
      for (int mt = 0; mt < 4; ++mt)
        af[mt] = *(const bf16x8*)&xs[(16 * mt + m) * XS_STRIDE + 32 * kt + q8];
#pragma unroll
      for (int t = 0; t < 4; ++t) {
        int nt = w + 16 * t;
        if (nt < NT_CAT) {
          bf16x8 bfr = *(const bf16x8*)(wcatp + ((size_t)(kt * NT_CAT + nt) * 64 + lane) * 8);
#pragma unroll
          for (int mt = 0; mt < 4; ++mt)
            acc[t][mt] = mfma16(af[mt], bfr, acc[t][mt]);
        }
      }
    }
#pragma unroll
    for (int t = 0; t < 4; ++t) {
      int nt = w + 16 * t;
      if (nt >= NT_CAT) continue;
      int c = nt * 16 + m;
      if (c < 256) {
#pragma unroll
        for (int mt = 0; mt < 4; ++mt)
#pragma unroll
          for (int r = 0; r < 4; ++r)
            qs[(16 * mt + 4 * q + r) * QK_STRIDE + c] = f2b(acc[t][mt][r]);
      } else if (c < 512) {
#pragma unroll
        for (int mt = 0; mt < 4; ++mt)
#pragma unroll
          for (int r = 0; r < 4; ++r)
            ks[(16 * mt + 4 * q + r) * QK_STRIDE + (c - 256)] = f2b(acc[t][mt][r]);
      } else if (c < 768) {
#pragma unroll
        for (int mt = 0; mt < 4; ++mt) {
          int frag = (nt - 32) * 2 + (mt >> 1);
          int q2 = (2 * mt + (q >> 1)) & 3;
          int j0 = 4 * (q & 1);
          s16x4 pk;
#pragma unroll
          for (int r = 0; r < 4; ++r) pk[r] = f2b(acc[t][mt][r]);
          *(s16x4*)&vs[frag * 512 + (q2 * 16 + m) * 8 + j0] = pk;
        }
      } else {
        if (m < 3) {
          float* dst = (m == 0) ? qd_s : (m == 1) ? kd_s : vd_s;
#pragma unroll
          for (int mt = 0; mt < 4; ++mt)
#pragma unroll
            for (int r = 0; r < 4; ++r)
              dst[16 * mt + 4 * q + r] = acc[t][mt][r];
        }
      }
    }
  }
  __syncthreads();

  const int rw = w & 3;
  const int hp = w >> 2;

  bf16x8 aq[2];
#pragma unroll
  for (int hh = 0; hh < 2; ++hh)
    aq[hh] = *(const bf16x8*)&qs[(16 * rw + m) * QK_STRIDE + 32 * (2 * hp + hh) + q8];

  float gate[4][4], ssum[4][4];
  {
    float qd_r[4], kd_c[4];
#pragma unroll
    for (int r = 0; r < 4; ++r) qd_r[r] = qd_s[16 * rw + 4 * q + r];
#pragma unroll
    for (int nt = 0; nt < 4; ++nt) kd_c[nt] = kd_s[16 * nt + m];
#pragma unroll
    for (int nt = 0; nt < 4; ++nt)
#pragma unroll
      for (int r = 0; r < 4; ++r) {
        float t = qd_r[r] * kd_c[nt];
        gate[nt][r] = 1.f / (1.f + __expf(-t));
        ssum[nt][r] = 0.f;
      }
  }
  __syncthreads();

  if (hp == 0) {
    bf16x8 z = {0, 0, 0, 0, 0, 0, 0, 0};
    *(bf16x8*)&oc[(16 * rw + m) * OC_STRIDE + 256 + q8] = z;
  }

  short* atw = (short*)(smem + QS_OFF) + w * (16 * AT_STRIDE);

#pragma unroll
  for (int hh = 0; hh < 2; ++hh) {
    int h = 2 * hp + hh;
    f32x4 sv[4];
#pragma unroll
    for (int nt = 0; nt < 4; ++nt) {
      bf16x8 bkf = *(const bf16x8*)&ks[(16 * nt + m) * QK_STRIDE + 32 * h + q8];
      f32x4 z = {0.f, 0.f, 0.f, 0.f};
      sv[nt] = mfma16(aq[hh], bkf, z);
    }
    float sm[4][4], mx[4], sum[4];
#pragma unroll
    for (int r = 0; r < 4; ++r) mx[r] = -3.4e38f;
#pragma unroll
    for (int nt = 0; nt < 4; ++nt)
#pragma unroll
      for (int r = 0; r < 4; ++r) {
        float s = sv[nt][r] * gate[nt][r];
        ssum[nt][r] += s;
        sm[nt][r] = s;
        mx[r] = fmaxf(mx[r], s);
      }
#pragma unroll
    for (int r = 0; r < 4; ++r) {
#pragma unroll
      for (int msk = 1; msk < 16; msk <<= 1)
        mx[r] = fmaxf(mx[r], __shfl_xor(mx[r], msk));
      sum[r] = 0.f;
    }
#pragma unroll
    for (int nt = 0; nt < 4; ++nt)
#pragma unroll
      for (int r = 0; r < 4; ++r) {
        float p = __expf(sm[nt][r] - mx[r]);
        sm[nt][r] = p;
        sum[r] += p;
      }
#pragma unroll
    for (int r = 0; r < 4; ++r) {
#pragma unroll
      for (int msk = 1; msk < 16; msk <<= 1)
        sum[r] += __shfl_xor(sum[r], msk);
      sum[r] = 1.f / sum[r];
    }
#pragma unroll
    for (int nt = 0; nt < 4; ++nt)
#pragma unroll
      for (int r = 0; r < 4; ++r)
        atw[(4 * q + r) * AT_STRIDE + 16 * nt + m] = f2b(sm[nt][r] * sum[r]);

    s16x4 l0 = *(const s16x4*)&atw[m * AT_STRIDE + q8];
    s16x4 l1 = *(const s16x4*)&atw[m * AT_STRIDE + q8 + 4];
    s16x4 l2 = *(const s16x4*)&atw[m * AT_STRIDE + 32 + q8];
    s16x4 l3 = *(const s16x4*)&atw[m * AT_STRIDE + 32 + q8 + 4];
    bf16x8 a0, a1;
#pragma unroll
    for (int j = 0; j < 4; ++j) { a0[j] = l0[j]; a0[4 + j] = l1[j]; a1[j] = l2[j]; a1[4 + j] = l3[j]; }

#pragma unroll
    for (int ntp = 0; ntp < 2; ++ntp) {
      bf16x8 bv0 = *(const bf16x8*)&vs[(((2 * h + ntp) * 2) + 0) * 512 + lane * 8];
      bf16x8 bv1 = *(const bf16x8*)&vs[(((2 * h + ntp) * 2) + 1) * 512 + lane * 8];
      f32x4 o = {0.f, 0.f, 0.f, 0.f};
      o = mfma16(a0, bv0, o);
      o = mfma16(a1, bv1, o);
#pragma unroll
      for (int r = 0; r < 4; ++r)
        oc[(16 * rw + 4 * q + r) * OC_STRIDE + 32 * h + 16 * ntp + m] = f2b(o[r]);
    }
  }

#pragma unroll
  for (int nt = 0; nt < 4; ++nt)
#pragma unroll
    for (int r = 0; r < 4; ++r)
      atomicAdd(&dsum[(16 * rw + 4 * q + r) * DS_STRIDE + 16 * nt + m], ssum[nt][r]);
  __syncthreads();

  if (hp == 0) {
    float sd[4][4], mx[4], sum[4];
#pragma unroll
    for (int nt = 0; nt < 4; ++nt)
#pragma unroll
      for (int r = 0; r < 4; ++r)
        sd[nt][r] = dsum[(16 * rw + 4 * q + r) * DS_STRIDE + 16 * nt + m];
#pragma unroll
    for (int r = 0; r < 4; ++r) mx[r] = -3.4e38f;
#pragma unroll
    for (int nt = 0; nt < 4; ++nt)
#pragma unroll
      for (int r = 0; r < 4; ++r) mx[r] = fmaxf(mx[r], sd[nt][r]);
#pragma unroll
    for (int r = 0; r < 4; ++r) {
#pragma unroll
      for (int msk = 1; msk < 16; msk <<= 1)
        mx[r] = fmaxf(mx[r], __shfl_xor(mx[r], msk));
      sum[r] = 0.f;
    }
#pragma unroll
    for (int nt = 0; nt < 4; ++nt)
#pragma unroll
      for (int r = 0; r < 4; ++r) {
        sd[nt][r] = __expf(sd[nt][r] - mx[r]);
        sum[r] += sd[nt][r];
      }
#pragma unroll
    for (int r = 0; r < 4; ++r) {
#pragma unroll
      for (int msk = 1; msk < 16; msk <<= 1)
        sum[r] += __shfl_xor(sum[r], msk);
      sum[r] = 1.f / sum[r];
    }
    float vd_c[4];
#pragma unroll
    for (int nt = 0; nt < 4; ++nt) vd_c[nt] = vd_s[16 * nt + m];
    float ov[4] = {0.f, 0.f, 0.f, 0.f};
#pragma unroll
    for (int nt = 0; nt < 4; ++nt)
#pragma unroll
      for (int r = 0; r < 4; ++r) ov[r] += sd[nt][r] * vd_c[nt];
#pragma unroll
    for (int r = 0; r < 4; ++r) {
#pragma unroll
      for (int msk = 1; msk < 16; msk <<= 1)
        ov[r] += __shfl_xor(ov[r], msk);
    }
    if (m == 0) {
#pragma unroll
      for (int r = 0; r < 4; ++r)
        oc[(16 * rw + 4 * q + r) * OC_STRIDE + 256] = f2b(ov[r] * sum[r]);
    }
  }
  __syncthreads();

  {
    f32x4 acc2[2][4];
#pragma unroll
    for (int t = 0; t < 2; ++t)
#pragma unroll
      for (int mt = 0; mt < 4; ++mt) acc2[t][mt] = f32x4{0.f, 0.f, 0.f, 0.f};

    for (int kt = 0; kt < KT; ++kt) {
      bf16x8 ao[4];
#pragma unroll
      for (int mt = 0; mt < 4; ++mt)
        ao[mt] = *(const bf16x8*)&oc[(16 * mt + m) * OC_STRIDE + 32 * kt + q8];
#pragma unroll
      for (int t = 0; t < 2; ++t) {
        int nt = w + 16 * t;
        if (nt < NT_OUT) {
          bf16x8 bw = *(const bf16x8*)(woutp + ((size_t)(kt * NT_OUT + nt) * 64 + lane) * 8);
#pragma unroll
          for (int mt = 0; mt < 4; ++mt)
            acc2[t][mt] = mfma16(ao[mt], bw, acc2[t][mt]);
        }
      }
    }
#pragma unroll
    for (int t = 0; t < 2; ++t) {
      int nt = w + 16 * t;
      if (nt >= NT_OUT) continue;
      int n = 16 * nt + m;
      if (n < D1) {
#pragma unroll
        for (int mt = 0; mt < 4; ++mt)
#pragma unroll
          for (int r = 0; r < 4; ++r)
            out[((size_t)win * NTOK + 16 * mt + 4 * q + r) * D1 + n] = acc2[t][mt][r];
      }
    }
  }
}

extern "C" void kernel_launch(void* const* d_in, const int* in_sizes, int n_in,
                              void* d_out, int out_size, void* d_ws, size_t ws_size,
                              hipStream_t stream) {
  (void)n_in; (void)out_size;
  const float* x    = (const float*)d_in[0];
  const float* Wqv  = (const float*)d_in[1];
  const float* Wkv  = (const float*)d_in[2];
  const float* Wvv  = (const float*)d_in[3];
  const float* Wqd  = (const float*)d_in[4];
  const float* Wkd  = (const float*)d_in[5];
  const float* Wvd  = (const float*)d_in[6];
  const float* Wout = (const float*)d_in[7];
  float* out = (float*)d_out;

  short* wcatp = (short*)d_ws;
  short* woutp = wcatp + WCAT_ELEMS;

  int nwin = in_sizes[0] / (NTOK * D1);         // 2048

  int prep_blocks = (WCAT_ELEMS + WOUT_ELEMS) / 256;   // 1188, exact
  prep_weights<<<prep_blocks, 256, 0, stream>>>(Wqv, Wkv, Wvv, Wqd, Wkd, Wvd, Wout, wcatp, woutp);

  // xbf chunking: 36,864 B per window after the weight region.
  const size_t woff = (size_t)(WCAT_ELEMS + WOUT_ELEMS) * 2;   // 608,256 B (16-aligned)
  const size_t per_win = (size_t)XWIN_ELEMS * 2;               // 36,864 B
  size_t avail = (ws_size > woff) ? ws_size - woff : 0;
  long long cwll = (long long)(avail / per_win);
  int cw = (cwll > nwin) ? nwin : (int)cwll;

  if (cw < 128) {
    // workspace too small -> R2 fused fallback
    hipFuncSetAttribute((const void*)vda_attn, hipFuncAttributeMaxDynamicSharedMemorySize, LDS_SIZE);
    vda_attn<<<nwin, 1024, LDS_SIZE, stream>>>(x, wcatp, woutp, out);
    return;
  }

  hipFuncSetAttribute((const void*)vda_attn2, hipFuncAttributeMaxDynamicSharedMemorySize, LDS2);
  short* xbf = (short*)((char*)d_ws + woff);

  for (int base = 0; base < nwin; base += cw) {
    int g = nwin - base;
    if (g > cw) g = cw;
    prep_x<<<dim3(72, g), 256, 0, stream>>>(x, xbf, base);
    vda_attn2<<<g, 1024, LDS2, stream>>>(xbf, wcatp, woutp, out, base);
  }
}

// Round 3
// 576.478 us; speedup vs baseline: 1.4197x; 1.0746x over previous
//
#include <hip/hip_runtime.h>

// VisualDepthAttention on MI355X (gfx950) — round 5.
// R4 post-mortem: kernel 385us (MfmaUtil 9.6, VALU 19.9, conflicts 12.9M->4.1M) but
// total 567->619: prep_x was 147K tiny blocks (~75us dispatch overhead).
// Root cause of the 385 plateau: register ceiling. 60 VGPR + 64 AGPR (acc[4][4]) = 124
// of the 128/wave a 1024-thr block allows -> compiler CANNOT pipeline the global
// B-fragment loads; every kt step exposes ~200-300cy L2 latency against ~80cy of MFMA.
// R5:
//  (1) Phase B split into two nt-passes (acc[2][4] = 32 AGPR) -> ~32 regs freed.
//  (2) Explicit 2-deep register prefetch of wcat/wout B-frags + 1-deep LDS A-frag
//      prefetch in phases B and D.
//  (3) First B-frags pre-issued BEFORE the preceding barrier (S1/S6): barrier drain
//      hides their latency.
//  (4) prep_x grid-stride (2016 blocks, element decode hoisted out of window loop).
// Everything else (layouts, attention math, barriers) identical to R4.

#define D1    257
#define NTOK  64
#define KT    9      // K padded to 288 = 9*32
#define NT_CAT 49    // Wcat N = 784 = 49*16
#define NT_OUT 17    // Wout N = 272 = 17*16
#define SCALE 0.17677669529663687f

// ---- fused kernel LDS layout (frag-linear). Total 154,624 <= 163,840 ----
#define XS2_OFF 0          // xs/oc: 36 frags x 1KB = 36,864 (frag = kt*4+mt)
#define QS2_OFF 36864      // qs: 32 frags x 1KB = 32,768; at overlay (16w x 2,176 = 34,816)
#define KS2_OFF 71680      // ks: 32 frags = 32,768
#define VS2_OFF 104448     // vs: 32 frags = 32,768 (B-frag-linear)
#define DS2_OFF 137216     // dsum fp32 [64][65] = 16,640
#define QD2_OFF 153856
#define KD2_OFF 154112
#define VD2_OFF 154368
#define LDS2    154624
#define AT_STRIDE 68
#define DS_STRIDE 65

// ---- R2 fallback LDS layout (verbatim) ----
#define XS_OFF    0
#define XS_STRIDE 296
#define OC_STRIDE 296
#define QS_OFF    37888
#define QK_STRIDE 264
#define KS_OFF    72704
#define VS_OFF    106496
#define DS_OFF    139264
#define QD_OFF    155904
#define KD_OFF    156160
#define VD_OFF    156416
#define LDS_SIZE  156672

#define WCAT_ELEMS (KT * NT_CAT * 512)   // 225792 bf16
#define WOUT_ELEMS (KT * NT_OUT * 512)   // 78336 bf16
#define XWIN_ELEMS (36 * 512)            // 18432 bf16 per window (frag-linear)

using bf16x8 = __attribute__((ext_vector_type(8))) short;
using s16x4  = __attribute__((ext_vector_type(4))) short;
using f32x4  = __attribute__((ext_vector_type(4))) float;

__device__ __forceinline__ short f2b(float f) {
  unsigned u = __float_as_uint(f);
  u = (u + 0x7FFFu + ((u >> 16) & 1u)) >> 16;   // RNE
  return (short)u;
}

__device__ __forceinline__ f32x4 mfma16(bf16x8 a, bf16x8 b, f32x4 c) {
  return __builtin_amdgcn_mfma_f32_16x16x32_bf16(a, b, c, 0, 0, 0);
}

// B-fragment load macros (16B/lane, lane-linear -> coalesced, conflict-free)
#define WFRAG(kt, nt) (*(const bf16x8*)(wcatp + ((size_t)((kt) * NT_CAT + (nt)) * 64 + lane) * 8))
#define OFRAG(kt, nt) (*(const bf16x8*)(woutp + ((size_t)((kt) * NT_OUT + (nt)) * 64 + lane) * 8))

__global__ void prep_weights(const float* __restrict__ Wqv, const float* __restrict__ Wkv,
                             const float* __restrict__ Wvv, const float* __restrict__ Wqd,
                             const float* __restrict__ Wkd, const float* __restrict__ Wvd,
                             const float* __restrict__ Wout,
                             short* __restrict__ wcatp, short* __restrict__ woutp) {
  int idx = blockIdx.x * 256 + threadIdx.x;
  if (idx < WCAT_ELEMS) {
    int j = idx & 7, lane = (idx >> 3) & 63, rest = idx >> 9;
    int nt = rest % NT_CAT, kt = rest / NT_CAT;
    int k = 32 * kt + (lane >> 4) * 8 + j;
    int n = 16 * nt + (lane & 15);
    float v = 0.f;
    if (k < D1) {
      if (n < 256)       v = Wqv[k * 256 + n] * SCALE;
      else if (n < 512)  v = Wkv[k * 256 + (n - 256)];
      else if (n < 768)  v = Wvv[k * 256 + (n - 512)];
      else if (n == 768) v = Wqd[k] * SCALE;
      else if (n == 769) v = Wkd[k];
      else if (n == 770) v = Wvd[k];
    }
    wcatp[idx] = f2b(v);
  } else {
    int i2 = idx - WCAT_ELEMS;
    int j = i2 & 7, lane = (i2 >> 3) & 63, rest = i2 >> 9;
    int nt = rest % NT_OUT, kt = rest / NT_OUT;
    int k = 32 * kt + (lane >> 4) * 8 + j;
    int n = 16 * nt + (lane & 15);
    float v = (k < D1 && n < D1) ? Wout[k * D1 + n] : 0.f;
    woutp[i2] = f2b(v);
  }
}

// x fp32 -> bf16 A-frag-linear per window. Grid-stride over windows; element decode
// hoisted (each thread owns one fixed element slot e, loops over windows).
// Launch with grid = 72 * WSTEP blocks of 256.
#define PX_WSTEP 28
__global__ __launch_bounds__(256)
void prep_x(const float* __restrict__ x, short* __restrict__ xbf, int win0, int nw) {
  const int e = (blockIdx.x % 72) * 256 + threadIdx.x;   // 0..18431
  const int j = e & 7, lane = (e >> 3) & 63, frag = e >> 9;
  const int kt = frag >> 2, mt = frag & 3;
  const int m = lane & 15, q = lane >> 4;
  const int row = 16 * mt + m;
  const int col = 32 * kt + 8 * q + j;
  const bool valid = (col < D1);
  const size_t xoff = (size_t)row * D1 + col;
  for (int widx = blockIdx.x / 72; widx < nw; widx += PX_WSTEP) {
    float v = valid ? x[(size_t)(win0 + widx) * (NTOK * D1) + xoff] : 0.f;
    xbf[(size_t)widx * XWIN_ELEMS + e] = f2b(v);
  }
}

// ======================= R5 fused kernel =======================
__global__ __launch_bounds__(1024)
void vda_attn2(const short* __restrict__ xbf, const short* __restrict__ wcatp,
               const short* __restrict__ woutp, float* __restrict__ out, int win0) {
  extern __shared__ char smem[];
  short* xs   = (short*)(smem + XS2_OFF);
  short* qs   = (short*)(smem + QS2_OFF);
  short* ks   = (short*)(smem + KS2_OFF);
  short* vs   = (short*)(smem + VS2_OFF);
  float* dsum = (float*)(smem + DS2_OFF);
  float* qd_s = (float*)(smem + QD2_OFF);
  float* kd_s = (float*)(smem + KD2_OFF);
  float* vd_s = (float*)(smem + VD2_OFF);
  short* oc = xs;

  const int tid  = threadIdx.x;
  const int lane = tid & 63;
  const int w    = tid >> 6;        // wave 0..15
  const int m    = lane & 15;
  const int q    = lane >> 4;
  const int q8   = q * 8;
  const int widx = blockIdx.x;
  const int win  = win0 + widx;

  // Pre-issue pass-0 B-frags (kt=0,1) BEFORE S1: barrier drain hides their latency.
  bf16x8 bA0 = WFRAG(0, w),      bA1 = WFRAG(1, w);
  bf16x8 bB0 = WFRAG(0, w + 16), bB1 = WFRAG(1, w + 16);

  // ---- Phase A: copy pre-converted frag-linear x + zero dsum.
  {
    const int4* src = (const int4*)(xbf + (size_t)widx * XWIN_ELEMS);
    int4* dst = (int4*)xs;
    for (int i = tid; i < 2304; i += 1024) dst[i] = src[i];   // 36,864 B
  }
  for (int i = tid; i < 64 * DS_STRIDE; i += 1024) dsum[i] = 0.f;
  __syncthreads();   // S1

  // ---- Phase B: C = xs[64x288] @ Wcat[288x784]. Two nt-passes, acc[2][4] (32 AGPR),
  // 2-deep global B-frag prefetch + 1-deep LDS A-frag prefetch.
  {
    // ================= pass 0: ntA = w (-> Q), ntB = w+16 (-> K) =================
    f32x4 acc[2][4];
#pragma unroll
    for (int t = 0; t < 2; ++t)
#pragma unroll
      for (int mt = 0; mt < 4; ++mt) acc[t][mt] = f32x4{0.f, 0.f, 0.f, 0.f};

    bf16x8 a_c[4];
#pragma unroll
    for (int mt = 0; mt < 4; ++mt)
      a_c[mt] = *(const bf16x8*)&xs[mt * 512 + lane * 8];

#pragma unroll
    for (int kt = 0; kt < KT; ++kt) {
      bf16x8 bA2{}, bB2{};
      if (kt + 2 < KT) {
        bA2 = WFRAG(kt + 2, w);
        bB2 = WFRAG(kt + 2, w + 16);
      }
      bf16x8 a_n[4];
      if (kt + 1 < KT) {
#pragma unroll
        for (int mt = 0; mt < 4; ++mt)
          a_n[mt] = *(const bf16x8*)&xs[((kt + 1) * 4 + mt) * 512 + lane * 8];
      }
#pragma unroll
      for (int mt = 0; mt < 4; ++mt) acc[0][mt] = mfma16(a_c[mt], bA0, acc[0][mt]);
#pragma unroll
      for (int mt = 0; mt < 4; ++mt) acc[1][mt] = mfma16(a_c[mt], bB0, acc[1][mt]);
      bA0 = bA1; bA1 = bA2; bB0 = bB1; bB1 = bB2;
      if (kt + 1 < KT) {
#pragma unroll
        for (int mt = 0; mt < 4; ++mt) a_c[mt] = a_n[mt];
      }
    }

    // Issue pass-1 prefetch now (overlaps pass-0 epilogue LDS writes).
    bf16x8 cA0 = WFRAG(0, w + 32), cA1 = WFRAG(1, w + 32);
    bf16x8 cB0{}, cB1{};
    if (w == 0) { cB0 = WFRAG(0, 48); cB1 = WFRAG(1, 48); }

    // pass-0 epilogue: Q (acc[0]) and K (acc[1]), frag-linear:
    // element (row,col16w+m) -> frag (col>>5)*4+(row>>4), slot (((col>>3)&3)*16+(row&15))*8+(col&7)
    {
      int cq = (2 * w + (m >> 3)) & 3;
      int jj = m & 7;
      int fb = (w >> 1) * 4;
#pragma unroll
      for (int mt = 0; mt < 4; ++mt)
#pragma unroll
        for (int r = 0; r < 4; ++r)
          qs[(fb + mt) * 512 + (cq * 16 + 4 * q + r) * 8 + jj] = f2b(acc[0][mt][r]);
#pragma unroll
      for (int mt = 0; mt < 4; ++mt)
#pragma unroll
        for (int r = 0; r < 4; ++r)
          ks[(fb + mt) * 512 + (cq * 16 + 4 * q + r) * 8 + jj] = f2b(acc[1][mt][r]);
    }

    // ================= pass 1: ntA = w+32 (-> V), ntB = 48 (w==0 -> depth) =================
#pragma unroll
    for (int t = 0; t < 2; ++t)
#pragma unroll
      for (int mt = 0; mt < 4; ++mt) acc[t][mt] = f32x4{0.f, 0.f, 0.f, 0.f};

#pragma unroll
    for (int mt = 0; mt < 4; ++mt)
      a_c[mt] = *(const bf16x8*)&xs[mt * 512 + lane * 8];

#pragma unroll
    for (int kt = 0; kt < KT; ++kt) {
      bf16x8 cA2{}, cB2{};
      if (kt + 2 < KT) {
        cA2 = WFRAG(kt + 2, w + 32);
        if (w == 0) cB2 = WFRAG(kt + 2, 48);
      }
      bf16x8 a_n[4];
      if (kt + 1 < KT) {
#pragma unroll
        for (int mt = 0; mt < 4; ++mt)
          a_n[mt] = *(const bf16x8*)&xs[((kt + 1) * 4 + mt) * 512 + lane * 8];
      }
#pragma unroll
      for (int mt = 0; mt < 4; ++mt) acc[0][mt] = mfma16(a_c[mt], cA0, acc[0][mt]);
      if (w == 0) {
#pragma unroll
        for (int mt = 0; mt < 4; ++mt) acc[1][mt] = mfma16(a_c[mt], cB0, acc[1][mt]);
      }
      cA0 = cA1; cA1 = cA2; cB0 = cB1; cB1 = cB2;
      if (kt + 1 < KT) {
#pragma unroll
        for (int mt = 0; mt < 4; ++mt) a_c[mt] = a_n[mt];
      }
    }

    // pass-1 epilogue: V B-frag-linear (proven layout)
#pragma unroll
    for (int mt = 0; mt < 4; ++mt) {
      int frag = w * 2 + (mt >> 1);
      int q2 = (2 * mt + (q >> 1)) & 3;
      int j0 = 4 * (q & 1);
      s16x4 pk;
#pragma unroll
      for (int r = 0; r < 4; ++r) pk[r] = f2b(acc[0][mt][r]);
      *(s16x4*)&vs[frag * 512 + (q2 * 16 + m) * 8 + j0] = pk;
    }
    // depth cols 768..770 (w==0 only)
    if (w == 0 && m < 3) {
      float* dst = (m == 0) ? qd_s : (m == 1) ? kd_s : vd_s;
#pragma unroll
      for (int mt = 0; mt < 4; ++mt)
#pragma unroll
        for (int r = 0; r < 4; ++r)
          dst[16 * mt + 4 * q + r] = acc[1][mt][r];
    }
  }
  __syncthreads();   // S2

  // ---- Phase C: wave = (rw = w&3 row tile, hp = w>>2 head pair {2hp, 2hp+1}).
  const int rw = w & 3;
  const int hp = w >> 2;

  bf16x8 aq[2];
#pragma unroll
  for (int hh = 0; hh < 2; ++hh)
    aq[hh] = *(const bf16x8*)&qs[(((2 * hp + hh) * 4 + rw)) * 512 + lane * 8];

  float gate[4][4], ssum[4][4];
  {
    float qd_r[4], kd_c[4];
#pragma unroll
    for (int r = 0; r < 4; ++r) qd_r[r] = qd_s[16 * rw + 4 * q + r];
#pragma unroll
    for (int nt = 0; nt < 4; ++nt) kd_c[nt] = kd_s[16 * nt + m];
#pragma unroll
    for (int nt = 0; nt < 4; ++nt)
#pragma unroll
      for (int r = 0; r < 4; ++r) {
        float t = qd_r[r] * kd_c[nt];
        gate[nt][r] = 1.f / (1.f + __expf(-t));
        ssum[nt][r] = 0.f;
      }
  }
  __syncthreads();   // S3 (qs dead -> at overlay live; oc (over xs) writable)

  if (hp == 0) {     // zero oc pad frags 32..35 (cols 256..287)
    int4 z4; z4.x = 0; z4.y = 0; z4.z = 0; z4.w = 0;
    ((int4*)(oc + 32 * 512))[rw * 64 + lane] = z4;
  }

  short* atw = (short*)(smem + QS2_OFF) + w * (16 * AT_STRIDE);

#pragma unroll
  for (int hh = 0; hh < 2; ++hh) {
    int h = 2 * hp + hh;
    f32x4 sv[4];
#pragma unroll
    for (int nt = 0; nt < 4; ++nt) {
      bf16x8 bk = *(const bf16x8*)&ks[(h * 4 + nt) * 512 + lane * 8];
      f32x4 z = {0.f, 0.f, 0.f, 0.f};
      sv[nt] = mfma16(aq[hh], bk, z);
    }
    float sm[4][4], mx[4], sum[4];
#pragma unroll
    for (int r = 0; r < 4; ++r) mx[r] = -3.4e38f;
#pragma unroll
    for (int nt = 0; nt < 4; ++nt)
#pragma unroll
      for (int r = 0; r < 4; ++r) {
        float s = sv[nt][r] * gate[nt][r];
        ssum[nt][r] += s;
        sm[nt][r] = s;
        mx[r] = fmaxf(mx[r], s);
      }
#pragma unroll
    for (int r = 0; r < 4; ++r) {
#pragma unroll
      for (int msk = 1; msk < 16; msk <<= 1)
        mx[r] = fmaxf(mx[r], __shfl_xor(mx[r], msk));
      sum[r] = 0.f;
    }
#pragma unroll
    for (int nt = 0; nt < 4; ++nt)
#pragma unroll
      for (int r = 0; r < 4; ++r) {
        float p = __expf(sm[nt][r] - mx[r]);
        sm[nt][r] = p;
        sum[r] += p;
      }
#pragma unroll
    for (int r = 0; r < 4; ++r) {
#pragma unroll
      for (int msk = 1; msk < 16; msk <<= 1)
        sum[r] += __shfl_xor(sum[r], msk);
      sum[r] = 1.f / sum[r];
    }
#pragma unroll
    for (int nt = 0; nt < 4; ++nt)
#pragma unroll
      for (int r = 0; r < 4; ++r)
        atw[(4 * q + r) * AT_STRIDE + 16 * nt + m] = f2b(sm[nt][r] * sum[r]);

    // A-frags of attn (wave-private LDS round trip)
    s16x4 l0 = *(const s16x4*)&atw[m * AT_STRIDE + q8];
    s16x4 l1 = *(const s16x4*)&atw[m * AT_STRIDE + q8 + 4];
    s16x4 l2 = *(const s16x4*)&atw[m * AT_STRIDE + 32 + q8];
    s16x4 l3 = *(const s16x4*)&atw[m * AT_STRIDE + 32 + q8 + 4];
    bf16x8 a0, a1;
#pragma unroll
    for (int j = 0; j < 4; ++j) { a0[j] = l0[j]; a0[4 + j] = l1[j]; a1[j] = l2[j]; a1[4 + j] = l3[j]; }

#pragma unroll
    for (int ntv = 0; ntv < 2; ++ntv) {
      bf16x8 bv0 = *(const bf16x8*)&vs[(((2 * h + ntv) * 2) + 0) * 512 + lane * 8];
      bf16x8 bv1 = *(const bf16x8*)&vs[(((2 * h + ntv) * 2) + 1) * 512 + lane * 8];
      f32x4 o = {0.f, 0.f, 0.f, 0.f};
      o = mfma16(a0, bv0, o);
      o = mfma16(a1, bv1, o);
      // oc frag-linear write: row=16rw+4q+r, col=32h+16ntv+m
      int cq2 = (2 * ntv + (m >> 3)) & 3;
#pragma unroll
      for (int r = 0; r < 4; ++r)
        oc[(h * 4 + rw) * 512 + (cq2 * 16 + 4 * q + r) * 8 + (m & 7)] = f2b(o[r]);
    }
  }

  // head-sum reduction across the 4 hp-waves sharing rw
#pragma unroll
  for (int nt = 0; nt < 4; ++nt)
#pragma unroll
    for (int r = 0; r < 4; ++r)
      atomicAdd(&dsum[(16 * rw + 4 * q + r) * DS_STRIDE + 16 * nt + m], ssum[nt][r]);
  __syncthreads();   // S5

  if (hp == 0) {     // attn_d softmax + out_d for rows 16rw..16rw+15
    float sd[4][4], mx[4], sum[4];
#pragma unroll
    for (int nt = 0; nt < 4; ++nt)
#pragma unroll
      for (int r = 0; r < 4; ++r)
        sd[nt][r] = dsum[(16 * rw + 4 * q + r) * DS_STRIDE + 16 * nt + m];
#pragma unroll
    for (int r = 0; r < 4; ++r) mx[r] = -3.4e38f;
#pragma unroll
    for (int nt = 0; nt < 4; ++nt)
#pragma unroll
      for (int r = 0; r < 4; ++r) mx[r] = fmaxf(mx[r], sd[nt][r]);
#pragma unroll
    for (int r = 0; r < 4; ++r) {
#pragma unroll
      for (int msk = 1; msk < 16; msk <<= 1)
        mx[r] = fmaxf(mx[r], __shfl_xor(mx[r], msk));
      sum[r] = 0.f;
    }
#pragma unroll
    for (int nt = 0; nt < 4; ++nt)
#pragma unroll
      for (int r = 0; r < 4; ++r) {
        sd[nt][r] = __expf(sd[nt][r] - mx[r]);
        sum[r] += sd[nt][r];
      }
#pragma unroll
    for (int r = 0; r < 4; ++r) {
#pragma unroll
      for (int msk = 1; msk < 16; msk <<= 1)
        sum[r] += __shfl_xor(sum[r], msk);
      sum[r] = 1.f / sum[r];
    }
    float vd_c[4];
#pragma unroll
    for (int nt = 0; nt < 4; ++nt) vd_c[nt] = vd_s[16 * nt + m];
    float ov[4] = {0.f, 0.f, 0.f, 0.f};
#pragma unroll
    for (int nt = 0; nt < 4; ++nt)
#pragma unroll
      for (int r = 0; r < 4; ++r) ov[r] += sd[nt][r] * vd_c[nt];
#pragma unroll
    for (int r = 0; r < 4; ++r) {
#pragma unroll
      for (int msk = 1; msk < 16; msk <<= 1)
        ov[r] += __shfl_xor(ov[r], msk);
    }
    if (m == 0) {
      // col 256 -> frag 32+rw, cq=0, j=0
#pragma unroll
      for (int r = 0; r < 4; ++r)
        oc[(32 + rw) * 512 + (4 * q + r) * 8] = f2b(ov[r] * sum[r]);
    }
  }

  // Pre-issue phase-D B-frags (kt=0,1) BEFORE S6: barrier drain hides their latency.
  bf16x8 dA0 = OFRAG(0, w), dA1 = OFRAG(1, w);
  bf16x8 dB0{}, dB1{};
  if (w == 0) { dB0 = OFRAG(0, 16); dB1 = OFRAG(1, 16); }
  __syncthreads();   // S6

  // ---- Phase D: out = oc[64x288] @ Wout[288x272]; wave w owns nt {w, 16 (w==0)}.
  // 2-deep global prefetch + 1-deep LDS A-frag prefetch.
  {
    f32x4 acc2[2][4];
#pragma unroll
    for (int t = 0; t < 2; ++t)
#pragma unroll
      for (int mt = 0; mt < 4; ++mt) acc2[t][mt] = f32x4{0.f, 0.f, 0.f, 0.f};

    bf16x8 ao_c[4];
#pragma unroll
    for (int mt = 0; mt < 4; ++mt)
      ao_c[mt] = *(const bf16x8*)&oc[mt * 512 + lane * 8];

#pragma unroll
    for (int kt = 0; kt < KT; ++kt) {
      bf16x8 dA2{}, dB2{};
      if (kt + 2 < KT) {
        dA2 = OFRAG(kt + 2, w);
        if (w == 0) dB2 = OFRAG(kt + 2, 16);
      }
      bf16x8 ao_n[4];
      if (kt + 1 < KT) {
#pragma unroll
        for (int mt = 0; mt < 4; ++mt)
          ao_n[mt] = *(const bf16x8*)&oc[((kt + 1) * 4 + mt) * 512 + lane * 8];
      }
#pragma unroll
      for (int mt = 0; mt < 4; ++mt) acc2[0][mt] = mfma16(ao_c[mt], dA0, acc2[0][mt]);
      if (w == 0) {
#pragma unroll
        for (int mt = 0; mt < 4; ++mt) acc2[1][mt] = mfma16(ao_c[mt], dB0, acc2[1][mt]);
      }
      dA0 = dA1; dA1 = dA2; dB0 = dB1; dB1 = dB2;
      if (kt + 1 < KT) {
#pragma unroll
        for (int mt = 0; mt < 4; ++mt) ao_c[mt] = ao_n[mt];
      }
    }

    // epilogue: t=0 -> n = 16w+m (always < 257); t=1 (w==0) -> n = 256+m (m==0 only)
    {
      int n = 16 * w + m;
#pragma unroll
      for (int mt = 0; mt < 4; ++mt)
#pragma unroll
        for (int r = 0; r < 4; ++r)
          out[((size_t)win * NTOK + 16 * mt + 4 * q + r) * D1 + n] = acc2[0][mt][r];
    }
    if (w == 0 && m == 0) {
#pragma unroll
      for (int mt = 0; mt < 4; ++mt)
#pragma unroll
        for (int r = 0; r < 4; ++r)
          out[((size_t)win * NTOK + 16 * mt + 4 * q + r) * D1 + 256] = acc2[1][mt][r];
    }
  }
}

// ======================= R2 fused fallback (verbatim) =======================
__global__ __launch_bounds__(1024)
void vda_attn(const float* __restrict__ x, const short* __restrict__ wcatp,
              const short* __restrict__ woutp, float* __restrict__ out) {
  extern __shared__ char smem[];
  short* xs  = (short*)(smem + XS_OFF);
  short* qs  = (short*)(smem + QS_OFF);
  short* ks  = (short*)(smem + KS_OFF);
  short* vs  = (short*)(smem + VS_OFF);
  float* dsum = (float*)(smem + DS_OFF);
  float* qd_s = (float*)(smem + QD_OFF);
  float* kd_s = (float*)(smem + KD_OFF);
  float* vd_s = (float*)(smem + VD_OFF);
  short* oc = xs;

  const int tid  = threadIdx.x;
  const int lane = tid & 63;
  const int w    = tid >> 6;
  const int m    = lane & 15;
  const int q    = lane >> 4;
  const int q8   = q * 8;
  const int win  = blockIdx.x;

  for (int i = tid; i < 64 * 39; i += 1024) {
    int r = i / 39, c = 257 + (i % 39);
    xs[r * XS_STRIDE + c] = 0;
  }
  for (int i = tid; i < 64 * DS_STRIDE; i += 1024) dsum[i] = 0.f;
  {
    const float4* xw4 = (const float4*)(x + (size_t)win * (NTOK * D1));
    for (int f4 = tid; f4 < 4112; f4 += 1024) {
      float4 v = xw4[f4];
      float vals[4] = {v.x, v.y, v.z, v.w};
      int o0 = f4 * 4;
      int r0 = o0 / D1, c0 = o0 - r0 * D1;
#pragma unroll
      for (int jj = 0; jj < 4; ++jj) {
        int c = c0 + jj, r = r0;
        if (c >= D1) { c -= D1; r += 1; }
        xs[r * XS_STRIDE + c] = f2b(vals[jj]);
      }
    }
  }
  __syncthreads();

  {
    f32x4 acc[4][4];
#pragma unroll
    for (int t = 0; t < 4; ++t)
#pragma unroll
      for (int mt = 0; mt < 4; ++mt) acc[t][mt] = f32x4{0.f, 0.f, 0.f, 0.f};

    for (int kt = 0; kt < KT; ++kt) {
      bf16x8 af[4];
#pragma unroll
      for (int mt = 0; mt < 4; ++mt)
        af[mt] = *(const bf16x8*)&xs[(16 * mt + m) * XS_STRIDE + 32 * kt + q8];
#pragma unroll
      for (int t = 0; t < 4; ++t) {
        int nt = w + 16 * t;
        if (nt < NT_CAT) {
          bf16x8 bfr = *(const bf16x8*)(wcatp + ((size_t)(kt * NT_CAT + nt) * 64 + lane) * 8);
#pragma unroll
          for (int mt = 0; mt < 4; ++mt)
            acc[t][mt] = mfma16(af[mt], bfr, acc[t][mt]);
        }
      }
    }
#pragma unroll
    for (int t = 0; t < 4; ++t) {
      int nt = w + 16 * t;
      if (nt >= NT_CAT) continue;
      int c = nt * 16 + m;
      if (c < 256) {
#pragma unroll
        for (int mt = 0; mt < 4; ++mt)
#pragma unroll
          for (int r = 0; r < 4; ++r)
            qs[(16 * mt + 4 * q + r) * QK_STRIDE + c] = f2b(acc[t][mt][r]);
      } else if (c < 512) {
#pragma unroll
        for (int mt = 0; mt < 4; ++mt)
#pragma unroll
          for (int r = 0; r < 4; ++r)
            ks[(16 * mt + 4 * q + r) * QK_STRIDE + (c - 256)] = f2b(acc[t][mt][r]);
      } else if (c < 768) {
#pragma unroll
        for (int mt = 0; mt < 4; ++mt) {
          int frag = (nt - 32) * 2 + (mt >> 1);
          int q2 = (2 * mt + (q >> 1)) & 3;
          int j0 = 4 * (q & 1);
          s16x4 pk;
#pragma unroll
          for (int r = 0; r < 4; ++r) pk[r] = f2b(acc[t][mt][r]);
          *(s16x4*)&vs[frag * 512 + (q2 * 16 + m) * 8 + j0] = pk;
        }
      } else {
        if (m < 3) {
          float* dst = (m == 0) ? qd_s : (m == 1) ? kd_s : vd_s;
#pragma unroll
          for (int mt = 0; mt < 4; ++mt)
#pragma unroll
            for (int r = 0; r < 4; ++r)
              dst[16 * mt + 4 * q + r] = acc[t][mt][r];
        }
      }
    }
  }
  __syncthreads();

  const int rw = w & 3;
  const int hp = w >> 2;

  bf16x8 aq[2];
#pragma unroll
  for (int hh = 0; hh < 2; ++hh)
    aq[hh] = *(const bf16x8*)&qs[(16 * rw + m) * QK_STRIDE + 32 * (2 * hp + hh) + q8];

  float gate[4][4], ssum[4][4];
  {
    float qd_r[4], kd_c[4];
#pragma unroll
    for (int r = 0; r < 4; ++r) qd_r[r] = qd_s[16 * rw + 4 * q + r];
#pragma unroll
    for (int nt = 0; nt < 4; ++nt) kd_c[nt] = kd_s[16 * nt + m];
#pragma unroll
    for (int nt = 0; nt < 4; ++nt)
#pragma unroll
      for (int r = 0; r < 4; ++r) {
        float t = qd_r[r] * kd_c[nt];
        gate[nt][r] = 1.f / (1.f + __expf(-t));
        ssum[nt][r] = 0.f;
      }
  }
  __syncthreads();

  if (hp == 0) {
    bf16x8 z = {0, 0, 0, 0, 0, 0, 0, 0};
    *(bf16x8*)&oc[(16 * rw + m) * OC_STRIDE + 256 + q8] = z;
  }

  short* atw = (short*)(smem + QS_OFF) + w * (16 * AT_STRIDE);

#pragma unroll
  for (int hh = 0; hh < 2; ++hh) {
    int h = 2 * hp + hh;
    f32x4 sv[4];
#pragma unroll
    for (int nt = 0; nt < 4; ++nt) {
      bf16x8 bkf = *(const bf16x8*)&ks[(16 * nt + m) * QK_STRIDE + 32 * h + q8];
      f32x4 z = {0.f, 0.f, 0.f, 0.f};
      sv[nt] = mfma16(aq[hh], bkf, z);
    }
    float sm[4][4], mx[4], sum[4];
#pragma unroll
    for (int r = 0; r < 4; ++r) mx[r] = -3.4e38f;
#pragma unroll
    for (int nt = 0; nt < 4; ++nt)
#pragma unroll
      for (int r = 0; r < 4; ++r) {
        float s = sv[nt][r] * gate[nt][r];
        ssum[nt][r] += s;
        sm[nt][r] = s;
        mx[r] = fmaxf(mx[r], s);
      }
#pragma unroll
    for (int r = 0; r < 4; ++r) {
#pragma unroll
      for (int msk = 1; msk < 16; msk <<= 1)
        mx[r] = fmaxf(mx[r], __shfl_xor(mx[r], msk));
      sum[r] = 0.f;
    }
#pragma unroll
    for (int nt = 0; nt < 4; ++nt)
#pragma unroll
      for (int r = 0; r < 4; ++r) {
        float p = __expf(sm[nt][r] - mx[r]);
        sm[nt][r] = p;
        sum[r] += p;
      }
#pragma unroll
    for (int r = 0; r < 4; ++r) {
#pragma unroll
      for (int msk = 1; msk < 16; msk <<= 1)
        sum[r] += __shfl_xor(sum[r], msk);
      sum[r] = 1.f / sum[r];
    }
#pragma unroll
    for (int nt = 0; nt < 4; ++nt)
#pragma unroll
      for (int r = 0; r < 4; ++r)
        atw[(4 * q + r) * AT_STRIDE + 16 * nt + m] = f2b(sm[nt][r] * sum[r]);

    s16x4 l0 = *(const s16x4*)&atw[m * AT_STRIDE + q8];
    s16x4 l1 = *(const s16x4*)&atw[m * AT_STRIDE + q8 + 4];
    s16x4 l2 = *(const s16x4*)&atw[m * AT_STRIDE + 32 + q8];
    s16x4 l3 = *(const s16x4*)&atw[m * AT_STRIDE + 32 + q8 + 4];
    bf16x8 a0, a1;
#pragma unroll
    for (int j = 0; j < 4; ++j) { a0[j] = l0[j]; a0[4 + j] = l1[j]; a1[j] = l2[j]; a1[4 + j] = l3[j]; }

#pragma unroll
    for (int ntp = 0; ntp < 2; ++ntp) {
      bf16x8 bv0 = *(const bf16x8*)&vs[(((2 * h + ntp) * 2) + 0) * 512 + lane * 8];
      bf16x8 bv1 = *(const bf16x8*)&vs[(((2 * h + ntp) * 2) + 1) * 512 + lane * 8];
      f32x4 o = {0.f, 0.f, 0.f, 0.f};
      o = mfma16(a0, bv0, o);
      o = mfma16(a1, bv1, o);
#pragma unroll
      for (int r = 0; r < 4; ++r)
        oc[(16 * rw + 4 * q + r) * OC_STRIDE + 32 * h + 16 * ntp + m] = f2b(o[r]);
    }
  }

#pragma unroll
  for (int nt = 0; nt < 4; ++nt)
#pragma unroll
    for (int r = 0; r < 4; ++r)
      atomicAdd(&dsum[(16 * rw + 4 * q + r) * DS_STRIDE + 16 * nt + m], ssum[nt][r]);
  __syncthreads();

  if (hp == 0) {
    float sd[4][4], mx[4], sum[4];
#pragma unroll
    for (int nt = 0; nt < 4; ++nt)
#pragma unroll
      for (int r = 0; r < 4; ++r)
        sd[nt][r] = dsum[(16 * rw + 4 * q + r) * DS_STRIDE + 16 * nt + m];
#pragma unroll
    for (int r = 0; r < 4; ++r) mx[r] = -3.4e38f;
#pragma unroll
    for (int nt = 0; nt < 4; ++nt)
#pragma unroll
      for (int r = 0; r < 4; ++r) mx[r] = fmaxf(mx[r], sd[nt][r]);
#pragma unroll
    for (int r = 0; r < 4; ++r) {
#pragma unroll
      for (int msk = 1; msk < 16; msk <<= 1)
        mx[r] = fmaxf(mx[r], __shfl_xor(mx[r], msk));
      sum[r] = 0.f;
    }
#pragma unroll
    for (int nt = 0; nt < 4; ++nt)
#pragma unroll
      for (int r = 0; r < 4; ++r) {
        sd[nt][r] = __expf(sd[nt][r] - mx[r]);
        sum[r] += sd[nt][r];
      }
#pragma unroll
    for (int r = 0; r < 4; ++r) {
#pragma unroll
      for (int msk = 1; msk < 16; msk <<= 1)
        sum[r] += __shfl_xor(sum[r], msk);
      sum[r] = 1.f / sum[r];
    }
    float vd_c[4];
#pragma unroll
    for (int nt = 0; nt < 4; ++nt) vd_c[nt] = vd_s[16 * nt + m];
    float ov[4] = {0.f, 0.f, 0.f, 0.f};
#pragma unroll
    for (int nt = 0; nt < 4; ++nt)
#pragma unroll
      for (int r = 0; r < 4; ++r) ov[r] += sd[nt][r] * vd_c[nt];
#pragma unroll
    for (int r = 0; r < 4; ++r) {
#pragma unroll
      for (int msk = 1; msk < 16; msk <<= 1)
        ov[r] += __shfl_xor(ov[r], msk);
    }
    if (m == 0) {
#pragma unroll
      for (int r = 0; r < 4; ++r)
        oc[(16 * rw + 4 * q + r) * OC_STRIDE + 256] = f2b(ov[r] * sum[r]);
    }
  }
  __syncthreads();

  {
    f32x4 acc2[2][4];
#pragma unroll
    for (int t = 0; t < 2; ++t)
#pragma unroll
      for (int mt = 0; mt < 4; ++mt) acc2[t][mt] = f32x4{0.f, 0.f, 0.f, 0.f};

    for (int kt = 0; kt < KT; ++kt) {
      bf16x8 ao[4];
#pragma unroll
      for (int mt = 0; mt < 4; ++mt)
        ao[mt] = *(const bf16x8*)&oc[(16 * mt + m) * OC_STRIDE + 32 * kt + q8];
#pragma unroll
      for (int t = 0; t < 2; ++t) {
        int nt = w + 16 * t;
        if (nt < NT_OUT) {
          bf16x8 bw = *(const bf16x8*)(woutp + ((size_t)(kt * NT_OUT + nt) * 64 + lane) * 8);
#pragma unroll
          for (int mt = 0; mt < 4; ++mt)
            acc2[t][mt] = mfma16(ao[mt], bw, acc2[t][mt]);
        }
      }
    }
#pragma unroll
    for (int t = 0; t < 2; ++t) {
      int nt = w + 16 * t;
      if (nt >= NT_OUT) continue;
      int n = 16 * nt + m;
      if (n < D1) {
#pragma unroll
        for (int mt = 0; mt < 4; ++mt)
#pragma unroll
          for (int r = 0; r < 4; ++r)
            out[((size_t)win * NTOK + 16 * mt + 4 * q + r) * D1 + n] = acc2[t][mt][r];
      }
    }
  }
}

extern "C" void kernel_launch(void* const* d_in, const int* in_sizes, int n_in,
                              void* d_out, int out_size, void* d_ws, size_t ws_size,
                              hipStream_t stream) {
  (void)n_in; (void)out_size;
  const float* x    = (const float*)d_in[0];
  const float* Wqv  = (const float*)d_in[1];
  const float* Wkv  = (const float*)d_in[2];
  const float* Wvv  = (const float*)d_in[3];
  const float* Wqd  = (const float*)d_in[4];
  const float* Wkd  = (const float*)d_in[5];
  const float* Wvd  = (const float*)d_in[6];
  const float* Wout = (const float*)d_in[7];
  float* out = (float*)d_out;

  short* wcatp = (short*)d_ws;
  short* woutp = wcatp + WCAT_ELEMS;

  int nwin = in_sizes[0] / (NTOK * D1);         // 2048

  int prep_blocks = (WCAT_ELEMS + WOUT_ELEMS) / 256;   // 1188, exact
  prep_weights<<<prep_blocks, 256, 0, stream>>>(Wqv, Wkv, Wvv, Wqd, Wkd, Wvd, Wout, wcatp, woutp);

  // xbf chunking: 36,864 B per window after the weight region.
  const size_t woff = (size_t)(WCAT_ELEMS + WOUT_ELEMS) * 2;   // 608,256 B (16-aligned)
  const size_t per_win = (size_t)XWIN_ELEMS * 2;               // 36,864 B
  size_t avail = (ws_size > woff) ? ws_size - woff : 0;
  long long cwll = (long long)(avail / per_win);
  int cw = (cwll > nwin) ? nwin : (int)cwll;

  if (cw < 128) {
    // workspace too small -> R2 fused fallback
    hipFuncSetAttribute((const void*)vda_attn, hipFuncAttributeMaxDynamicSharedMemorySize, LDS_SIZE);
    vda_attn<<<nwin, 1024, LDS_SIZE, stream>>>(x, wcatp, woutp, out);
    return;
  }

  hipFuncSetAttribute((const void*)vda_attn2, hipFuncAttributeMaxDynamicSharedMemorySize, LDS2);
  short* xbf = (short*)((char*)d_ws + woff);

  for (int base = 0; base < nwin; base += cw) {
    int g = nwin - base;
    if (g > cw) g = cw;
    prep_x<<<72 * PX_WSTEP, 256, 0, stream>>>(x, xbf, base, g);
    vda_attn2<<<g, 1024, LDS2, stream>>>(xbf, wcatp, woutp, out, base);
  }
}

// Round 4
// 550.411 us; speedup vs baseline: 1.4869x; 1.0474x over previous
//
#include <hip/hip_runtime.h>

// VisualDepthAttention on MI355X (gfx950) — round 6.
// R5 post-mortem: kernel 343us (prefetch worked, VGPR 56). But total-kernel gap stayed
// 233us in BOTH R4 and R5 -> prep_x (~74us) is memory-PATTERN-bound (32B segments +
// 151MB xbf round trip), not dispatch-bound; remaining ~159us gap is constant harness
// overhead (present since R2 with 1 dispatch).
// R6: inline x staging back into the fused kernel — coalesced float4 reads of x,
// direct frag-linear LDS writes (R4 conflict-free layout, ~10 int ops/elem decode).
// Deletes prep_x + 151MB HBM round trip + extra dispatch. Zero-pass + barrier before
// staging (c=256 writes land inside pad frags 32..35). R5 prefetch structure kept.

#define D1    257
#define NTOK  64
#define KT    9      // K padded to 288 = 9*32
#define NT_CAT 49    // Wcat N = 784 = 49*16
#define NT_OUT 17    // Wout N = 272 = 17*16
#define SCALE 0.17677669529663687f

// ---- fused kernel LDS layout (frag-linear). Total 154,624 <= 163,840 ----
#define XS2_OFF 0          // xs/oc: 36 frags x 1KB = 36,864 (frag = kt*4+mt)
#define QS2_OFF 36864      // qs: 32 frags x 1KB = 32,768; at overlay (16w x 2,176 = 34,816)
#define KS2_OFF 71680      // ks: 32 frags = 32,768
#define VS2_OFF 104448     // vs: 32 frags = 32,768 (B-frag-linear)
#define DS2_OFF 137216     // dsum fp32 [64][65] = 16,640
#define QD2_OFF 153856
#define KD2_OFF 154112
#define VD2_OFF 154368
#define LDS2    154624
#define AT_STRIDE 68
#define DS_STRIDE 65

#define WCAT_ELEMS (KT * NT_CAT * 512)   // 225792 bf16
#define WOUT_ELEMS (KT * NT_OUT * 512)   // 78336 bf16

using bf16x8 = __attribute__((ext_vector_type(8))) short;
using s16x4  = __attribute__((ext_vector_type(4))) short;
using f32x4  = __attribute__((ext_vector_type(4))) float;

__device__ __forceinline__ short f2b(float f) {
  unsigned u = __float_as_uint(f);
  u = (u + 0x7FFFu + ((u >> 16) & 1u)) >> 16;   // RNE
  return (short)u;
}

__device__ __forceinline__ f32x4 mfma16(bf16x8 a, bf16x8 b, f32x4 c) {
  return __builtin_amdgcn_mfma_f32_16x16x32_bf16(a, b, c, 0, 0, 0);
}

// B-fragment load macros (16B/lane, lane-linear -> coalesced, conflict-free)
#define WFRAG(kt, nt) (*(const bf16x8*)(wcatp + ((size_t)((kt) * NT_CAT + (nt)) * 64 + lane) * 8))
#define OFRAG(kt, nt) (*(const bf16x8*)(woutp + ((size_t)((kt) * NT_OUT + (nt)) * 64 + lane) * 8))

__global__ void prep_weights(const float* __restrict__ Wqv, const float* __restrict__ Wkv,
                             const float* __restrict__ Wvv, const float* __restrict__ Wqd,
                             const float* __restrict__ Wkd, const float* __restrict__ Wvd,
                             const float* __restrict__ Wout,
                             short* __restrict__ wcatp, short* __restrict__ woutp) {
  int idx = blockIdx.x * 256 + threadIdx.x;
  if (idx < WCAT_ELEMS) {
    int j = idx & 7, lane = (idx >> 3) & 63, rest = idx >> 9;
    int nt = rest % NT_CAT, kt = rest / NT_CAT;
    int k = 32 * kt + (lane >> 4) * 8 + j;
    int n = 16 * nt + (lane & 15);
    float v = 0.f;
    if (k < D1) {
      if (n < 256)       v = Wqv[k * 256 + n] * SCALE;
      else if (n < 512)  v = Wkv[k * 256 + (n - 256)];
      else if (n < 768)  v = Wvv[k * 256 + (n - 512)];
      else if (n == 768) v = Wqd[k] * SCALE;
      else if (n == 769) v = Wkd[k];
      else if (n == 770) v = Wvd[k];
    }
    wcatp[idx] = f2b(v);
  } else {
    int i2 = idx - WCAT_ELEMS;
    int j = i2 & 7, lane = (i2 >> 3) & 63, rest = i2 >> 9;
    int nt = rest % NT_OUT, kt = rest / NT_OUT;
    int k = 32 * kt + (lane >> 4) * 8 + j;
    int n = 16 * nt + (lane & 15);
    float v = (k < D1 && n < D1) ? Wout[k * D1 + n] : 0.f;
    woutp[i2] = f2b(v);
  }
}

// ======================= R6 fused kernel =======================
__global__ __launch_bounds__(1024)
void vda_attn2(const float* __restrict__ x, const short* __restrict__ wcatp,
               const short* __restrict__ woutp, float* __restrict__ out) {
  extern __shared__ char smem[];
  short* xs   = (short*)(smem + XS2_OFF);
  short* qs   = (short*)(smem + QS2_OFF);
  short* ks   = (short*)(smem + KS2_OFF);
  short* vs   = (short*)(smem + VS2_OFF);
  float* dsum = (float*)(smem + DS2_OFF);
  float* qd_s = (float*)(smem + QD2_OFF);
  float* kd_s = (float*)(smem + KD2_OFF);
  float* vd_s = (float*)(smem + VD2_OFF);
  short* oc = xs;

  const int tid  = threadIdx.x;
  const int lane = tid & 63;
  const int w    = tid >> 6;        // wave 0..15
  const int m    = lane & 15;
  const int q    = lane >> 4;
  const int q8   = q * 8;
  const int win  = blockIdx.x;

  // Pre-issue pass-0 B-frags (kt=0,1) at kernel start: the entire staging phase
  // hides their latency.
  bf16x8 bA0 = WFRAG(0, w),      bA1 = WFRAG(1, w);
  bf16x8 bB0 = WFRAG(0, w + 16), bB1 = WFRAG(1, w + 16);

  // ---- Phase A0: zero xs (incl. K-pad frags) + dsum. Barrier-ordered before
  // staging because staged c==256 elements land inside pad frags 32..35.
  {
    int4 z4; z4.x = 0; z4.y = 0; z4.z = 0; z4.w = 0;
    int4* xz = (int4*)xs;
    for (int i = tid; i < 2304; i += 1024) xz[i] = z4;
  }
  for (int i = tid; i < 64 * DS_STRIDE; i += 1024) dsum[i] = 0.f;
  __syncthreads();   // S0

  // ---- Phase A1: stage x (64x257 fp32), coalesced float4 reads, frag-linear
  // LDS writes: (r,c) -> ((c>>5)*4+(r>>4))*512 + (((c>>3)&3)*16+(r&15))*8 + (c&7).
  {
    const float4* xw4 = (const float4*)(x + (size_t)win * (NTOK * D1));
    for (int f4 = tid; f4 < 4112; f4 += 1024) {
      float4 v = xw4[f4];
      float vals[4] = {v.x, v.y, v.z, v.w};
      int o0 = f4 * 4;
      int r0 = o0 / D1, c0 = o0 - r0 * D1;
#pragma unroll
      for (int jj = 0; jj < 4; ++jj) {
        int c = c0 + jj, r = r0;
        if (c >= D1) { c -= D1; r += 1; }
        int idx = ((c >> 5) * 4 + (r >> 4)) * 512 + (((c >> 3) & 3) * 16 + (r & 15)) * 8 + (c & 7);
        xs[idx] = f2b(vals[jj]);
      }
    }
  }
  __syncthreads();   // S1

  // ---- Phase B: C = xs[64x288] @ Wcat[288x784]. Two nt-passes, acc[2][4] (32 AGPR),
  // 2-deep global B-frag prefetch + 1-deep LDS A-frag prefetch.
  {
    // ================= pass 0: ntA = w (-> Q), ntB = w+16 (-> K) =================
    f32x4 acc[2][4];
#pragma unroll
    for (int t = 0; t < 2; ++t)
#pragma unroll
      for (int mt = 0; mt < 4; ++mt) acc[t][mt] = f32x4{0.f, 0.f, 0.f, 0.f};

    bf16x8 a_c[4];
#pragma unroll
    for (int mt = 0; mt < 4; ++mt)
      a_c[mt] = *(const bf16x8*)&xs[mt * 512 + lane * 8];

#pragma unroll
    for (int kt = 0; kt < KT; ++kt) {
      bf16x8 bA2{}, bB2{};
      if (kt + 2 < KT) {
        bA2 = WFRAG(kt + 2, w);
        bB2 = WFRAG(kt + 2, w + 16);
      }
      bf16x8 a_n[4];
      if (kt + 1 < KT) {
#pragma unroll
        for (int mt = 0; mt < 4; ++mt)
          a_n[mt] = *(const bf16x8*)&xs[((kt + 1) * 4 + mt) * 512 + lane * 8];
      }
#pragma unroll
      for (int mt = 0; mt < 4; ++mt) acc[0][mt] = mfma16(a_c[mt], bA0, acc[0][mt]);
#pragma unroll
      for (int mt = 0; mt < 4; ++mt) acc[1][mt] = mfma16(a_c[mt], bB0, acc[1][mt]);
      bA0 = bA1; bA1 = bA2; bB0 = bB1; bB1 = bB2;
      if (kt + 1 < KT) {
#pragma unroll
        for (int mt = 0; mt < 4; ++mt) a_c[mt] = a_n[mt];
      }
    }

    // Issue pass-1 prefetch now (overlaps pass-0 epilogue LDS writes).
    bf16x8 cA0 = WFRAG(0, w + 32), cA1 = WFRAG(1, w + 32);
    bf16x8 cB0{}, cB1{};
    if (w == 0) { cB0 = WFRAG(0, 48); cB1 = WFRAG(1, 48); }

    // pass-0 epilogue: Q (acc[0]) and K (acc[1]), frag-linear.
    {
      int cq = (2 * w + (m >> 3)) & 3;
      int jj = m & 7;
      int fb = (w >> 1) * 4;
#pragma unroll
      for (int mt = 0; mt < 4; ++mt)
#pragma unroll
        for (int r = 0; r < 4; ++r)
          qs[(fb + mt) * 512 + (cq * 16 + 4 * q + r) * 8 + jj] = f2b(acc[0][mt][r]);
#pragma unroll
      for (int mt = 0; mt < 4; ++mt)
#pragma unroll
        for (int r = 0; r < 4; ++r)
          ks[(fb + mt) * 512 + (cq * 16 + 4 * q + r) * 8 + jj] = f2b(acc[1][mt][r]);
    }

    // ================= pass 1: ntA = w+32 (-> V), ntB = 48 (w==0 -> depth) =================
#pragma unroll
    for (int t = 0; t < 2; ++t)
#pragma unroll
      for (int mt = 0; mt < 4; ++mt) acc[t][mt] = f32x4{0.f, 0.f, 0.f, 0.f};

#pragma unroll
    for (int mt = 0; mt < 4; ++mt)
      a_c[mt] = *(const bf16x8*)&xs[mt * 512 + lane * 8];

#pragma unroll
    for (int kt = 0; kt < KT; ++kt) {
      bf16x8 cA2{}, cB2{};
      if (kt + 2 < KT) {
        cA2 = WFRAG(kt + 2, w + 32);
        if (w == 0) cB2 = WFRAG(kt + 2, 48);
      }
      bf16x8 a_n[4];
      if (kt + 1 < KT) {
#pragma unroll
        for (int mt = 0; mt < 4; ++mt)
          a_n[mt] = *(const bf16x8*)&xs[((kt + 1) * 4 + mt) * 512 + lane * 8];
      }
#pragma unroll
      for (int mt = 0; mt < 4; ++mt) acc[0][mt] = mfma16(a_c[mt], cA0, acc[0][mt]);
      if (w == 0) {
#pragma unroll
        for (int mt = 0; mt < 4; ++mt) acc[1][mt] = mfma16(a_c[mt], cB0, acc[1][mt]);
      }
      cA0 = cA1; cA1 = cA2; cB0 = cB1; cB1 = cB2;
      if (kt + 1 < KT) {
#pragma unroll
        for (int mt = 0; mt < 4; ++mt) a_c[mt] = a_n[mt];
      }
    }

    // pass-1 epilogue: V B-frag-linear (proven layout)
#pragma unroll
    for (int mt = 0; mt < 4; ++mt) {
      int frag = w * 2 + (mt >> 1);
      int q2 = (2 * mt + (q >> 1)) & 3;
      int j0 = 4 * (q & 1);
      s16x4 pk;
#pragma unroll
      for (int r = 0; r < 4; ++r) pk[r] = f2b(acc[0][mt][r]);
      *(s16x4*)&vs[frag * 512 + (q2 * 16 + m) * 8 + j0] = pk;
    }
    // depth cols 768..770 (w==0 only)
    if (w == 0 && m < 3) {
      float* dst = (m == 0) ? qd_s : (m == 1) ? kd_s : vd_s;
#pragma unroll
      for (int mt = 0; mt < 4; ++mt)
#pragma unroll
        for (int r = 0; r < 4; ++r)
          dst[16 * mt + 4 * q + r] = acc[1][mt][r];
    }
  }
  __syncthreads();   // S2

  // ---- Phase C: wave = (rw = w&3 row tile, hp = w>>2 head pair {2hp, 2hp+1}).
  const int rw = w & 3;
  const int hp = w >> 2;

  bf16x8 aq[2];
#pragma unroll
  for (int hh = 0; hh < 2; ++hh)
    aq[hh] = *(const bf16x8*)&qs[(((2 * hp + hh) * 4 + rw)) * 512 + lane * 8];

  float gate[4][4], ssum[4][4];
  {
    float qd_r[4], kd_c[4];
#pragma unroll
    for (int r = 0; r < 4; ++r) qd_r[r] = qd_s[16 * rw + 4 * q + r];
#pragma unroll
    for (int nt = 0; nt < 4; ++nt) kd_c[nt] = kd_s[16 * nt + m];
#pragma unroll
    for (int nt = 0; nt < 4; ++nt)
#pragma unroll
      for (int r = 0; r < 4; ++r) {
        float t = qd_r[r] * kd_c[nt];
        gate[nt][r] = 1.f / (1.f + __expf(-t));
        ssum[nt][r] = 0.f;
      }
  }
  __syncthreads();   // S3 (qs dead -> at overlay live; oc (over xs) writable)

  if (hp == 0) {     // zero oc pad frags 32..35 (cols 256..287)
    int4 z4; z4.x = 0; z4.y = 0; z4.z = 0; z4.w = 0;
    ((int4*)(oc + 32 * 512))[rw * 64 + lane] = z4;
  }

  short* atw = (short*)(smem + QS2_OFF) + w * (16 * AT_STRIDE);

#pragma unroll
  for (int hh = 0; hh < 2; ++hh) {
    int h = 2 * hp + hh;
    f32x4 sv[4];
#pragma unroll
    for (int nt = 0; nt < 4; ++nt) {
      bf16x8 bk = *(const bf16x8*)&ks[(h * 4 + nt) * 512 + lane * 8];
      f32x4 z = {0.f, 0.f, 0.f, 0.f};
      sv[nt] = mfma16(aq[hh], bk, z);
    }
    float sm[4][4], mx[4], sum[4];
#pragma unroll
    for (int r = 0; r < 4; ++r) mx[r] = -3.4e38f;
#pragma unroll
    for (int nt = 0; nt < 4; ++nt)
#pragma unroll
      for (int r = 0; r < 4; ++r) {
        float s = sv[nt][r] * gate[nt][r];
        ssum[nt][r] += s;
        sm[nt][r] = s;
        mx[r] = fmaxf(mx[r], s);
      }
#pragma unroll
    for (int r = 0; r < 4; ++r) {
#pragma unroll
      for (int msk = 1; msk < 16; msk <<= 1)
        mx[r] = fmaxf(mx[r], __shfl_xor(mx[r], msk));
      sum[r] = 0.f;
    }
#pragma unroll
    for (int nt = 0; nt < 4; ++nt)
#pragma unroll
      for (int r = 0; r < 4; ++r) {
        float p = __expf(sm[nt][r] - mx[r]);
        sm[nt][r] = p;
        sum[r] += p;
      }
#pragma unroll
    for (int r = 0; r < 4; ++r) {
#pragma unroll
      for (int msk = 1; msk < 16; msk <<= 1)
        sum[r] += __shfl_xor(sum[r], msk);
      sum[r] = 1.f / sum[r];
    }
#pragma unroll
    for (int nt = 0; nt < 4; ++nt)
#pragma unroll
      for (int r = 0; r < 4; ++r)
        atw[(4 * q + r) * AT_STRIDE + 16 * nt + m] = f2b(sm[nt][r] * sum[r]);

    // A-frags of attn (wave-private LDS round trip)
    s16x4 l0 = *(const s16x4*)&atw[m * AT_STRIDE + q8];
    s16x4 l1 = *(const s16x4*)&atw[m * AT_STRIDE + q8 + 4];
    s16x4 l2 = *(const s16x4*)&atw[m * AT_STRIDE + 32 + q8];
    s16x4 l3 = *(const s16x4*)&atw[m * AT_STRIDE + 32 + q8 + 4];
    bf16x8 a0, a1;
#pragma unroll
    for (int j = 0; j < 4; ++j) { a0[j] = l0[j]; a0[4 + j] = l1[j]; a1[j] = l2[j]; a1[4 + j] = l3[j]; }

#pragma unroll
    for (int ntv = 0; ntv < 2; ++ntv) {
      bf16x8 bv0 = *(const bf16x8*)&vs[(((2 * h + ntv) * 2) + 0) * 512 + lane * 8];
      bf16x8 bv1 = *(const bf16x8*)&vs[(((2 * h + ntv) * 2) + 1) * 512 + lane * 8];
      f32x4 o = {0.f, 0.f, 0.f, 0.f};
      o = mfma16(a0, bv0, o);
      o = mfma16(a1, bv1, o);
      // oc frag-linear write: row=16rw+4q+r, col=32h+16ntv+m
      int cq2 = (2 * ntv + (m >> 3)) & 3;
#pragma unroll
      for (int r = 0; r < 4; ++r)
        oc[(h * 4 + rw) * 512 + (cq2 * 16 + 4 * q + r) * 8 + (m & 7)] = f2b(o[r]);
    }
  }

  // head-sum reduction across the 4 hp-waves sharing rw
#pragma unroll
  for (int nt = 0; nt < 4; ++nt)
#pragma unroll
    for (int r = 0; r < 4; ++r)
      atomicAdd(&dsum[(16 * rw + 4 * q + r) * DS_STRIDE + 16 * nt + m], ssum[nt][r]);
  __syncthreads();   // S5

  if (hp == 0) {     // attn_d softmax + out_d for rows 16rw..16rw+15
    float sd[4][4], mx[4], sum[4];
#pragma unroll
    for (int nt = 0; nt < 4; ++nt)
#pragma unroll
      for (int r = 0; r < 4; ++r)
        sd[nt][r] = dsum[(16 * rw + 4 * q + r) * DS_STRIDE + 16 * nt + m];
#pragma unroll
    for (int r = 0; r < 4; ++r) mx[r] = -3.4e38f;
#pragma unroll
    for (int nt = 0; nt < 4; ++nt)
#pragma unroll
      for (int r = 0; r < 4; ++r) mx[r] = fmaxf(mx[r], sd[nt][r]);
#pragma unroll
    for (int r = 0; r < 4; ++r) {
#pragma unroll
      for (int msk = 1; msk < 16; msk <<= 1)
        mx[r] = fmaxf(mx[r], __shfl_xor(mx[r], msk));
      sum[r] = 0.f;
    }
#pragma unroll
    for (int nt = 0; nt < 4; ++nt)
#pragma unroll
      for (int r = 0; r < 4; ++r) {
        sd[nt][r] = __expf(sd[nt][r] - mx[r]);
        sum[r] += sd[nt][r];
      }
#pragma unroll
    for (int r = 0; r < 4; ++r) {
#pragma unroll
      for (int msk = 1; msk < 16; msk <<= 1)
        sum[r] += __shfl_xor(sum[r], msk);
      sum[r] = 1.f / sum[r];
    }
    float vd_c[4];
#pragma unroll
    for (int nt = 0; nt < 4; ++nt) vd_c[nt] = vd_s[16 * nt + m];
    float ov[4] = {0.f, 0.f, 0.f, 0.f};
#pragma unroll
    for (int nt = 0; nt < 4; ++nt)
#pragma unroll
      for (int r = 0; r < 4; ++r) ov[r] += sd[nt][r] * vd_c[nt];
#pragma unroll
    for (int r = 0; r < 4; ++r) {
#pragma unroll
      for (int msk = 1; msk < 16; msk <<= 1)
        ov[r] += __shfl_xor(ov[r], msk);
    }
    if (m == 0) {
      // col 256 -> frag 32+rw, cq=0, j=0
#pragma unroll
      for (int r = 0; r < 4; ++r)
        oc[(32 + rw) * 512 + (4 * q + r) * 8] = f2b(ov[r] * sum[r]);
    }
  }

  // Pre-issue phase-D B-frags (kt=0,1) BEFORE S6: barrier drain hides their latency.
  bf16x8 dA0 = OFRAG(0, w), dA1 = OFRAG(1, w);
  bf16x8 dB0{}, dB1{};
  if (w == 0) { dB0 = OFRAG(0, 16); dB1 = OFRAG(1, 16); }
  __syncthreads();   // S6

  // ---- Phase D: out = oc[64x288] @ Wout[288x272]; wave w owns nt {w, 16 (w==0)}.
  // 2-deep global prefetch + 1-deep LDS A-frag prefetch.
  {
    f32x4 acc2[2][4];
#pragma unroll
    for (int t = 0; t < 2; ++t)
#pragma unroll
      for (int mt = 0; mt < 4; ++mt) acc2[t][mt] = f32x4{0.f, 0.f, 0.f, 0.f};

    bf16x8 ao_c[4];
#pragma unroll
    for (int mt = 0; mt < 4; ++mt)
      ao_c[mt] = *(const bf16x8*)&oc[mt * 512 + lane * 8];

#pragma unroll
    for (int kt = 0; kt < KT; ++kt) {
      bf16x8 dA2{}, dB2{};
      if (kt + 2 < KT) {
        dA2 = OFRAG(kt + 2, w);
        if (w == 0) dB2 = OFRAG(kt + 2, 16);
      }
      bf16x8 ao_n[4];
      if (kt + 1 < KT) {
#pragma unroll
        for (int mt = 0; mt < 4; ++mt)
          ao_n[mt] = *(const bf16x8*)&oc[((kt + 1) * 4 + mt) * 512 + lane * 8];
      }
#pragma unroll
      for (int mt = 0; mt < 4; ++mt) acc2[0][mt] = mfma16(ao_c[mt], dA0, acc2[0][mt]);
      if (w == 0) {
#pragma unroll
        for (int mt = 0; mt < 4; ++mt) acc2[1][mt] = mfma16(ao_c[mt], dB0, acc2[1][mt]);
      }
      dA0 = dA1; dA1 = dA2; dB0 = dB1; dB1 = dB2;
      if (kt + 1 < KT) {
#pragma unroll
        for (int mt = 0; mt < 4; ++mt) ao_c[mt] = ao_n[mt];
      }
    }

    // epilogue: t=0 -> n = 16w+m (always < 256); t=1 (w==0) -> n = 256 (m==0 only)
    {
      int n = 16 * w + m;
#pragma unroll
      for (int mt = 0; mt < 4; ++mt)
#pragma unroll
        for (int r = 0; r < 4; ++r)
          out[((size_t)win * NTOK + 16 * mt + 4 * q + r) * D1 + n] = acc2[0][mt][r];
    }
    if (w == 0 && m == 0) {
#pragma unroll
      for (int mt = 0; mt < 4; ++mt)
#pragma unroll
        for (int r = 0; r < 4; ++r)
          out[((size_t)win * NTOK + 16 * mt + 4 * q + r) * D1 + 256] = acc2[1][mt][r];
    }
  }
}

extern "C" void kernel_launch(void* const* d_in, const int* in_sizes, int n_in,
                              void* d_out, int out_size, void* d_ws, size_t ws_size,
                              hipStream_t stream) {
  (void)n_in; (void)out_size; (void)ws_size;
  const float* x    = (const float*)d_in[0];
  const float* Wqv  = (const float*)d_in[1];
  const float* Wkv  = (const float*)d_in[2];
  const float* Wvv  = (const float*)d_in[3];
  const float* Wqd  = (const float*)d_in[4];
  const float* Wkd  = (const float*)d_in[5];
  const float* Wvd  = (const float*)d_in[6];
  const float* Wout = (const float*)d_in[7];
  float* out = (float*)d_out;

  short* wcatp = (short*)d_ws;                  // 608,256 B total for weights
  short* woutp = wcatp + WCAT_ELEMS;

  int nwin = in_sizes[0] / (NTOK * D1);         // 2048

  int prep_blocks = (WCAT_ELEMS + WOUT_ELEMS) / 256;   // 1188, exact
  prep_weights<<<prep_blocks, 256, 0, stream>>>(Wqv, Wkv, Wvv, Wqd, Wkd, Wvd, Wout, wcatp, woutp);

  hipFuncSetAttribute((const void*)vda_attn2, hipFuncAttributeMaxDynamicSharedMemorySize, LDS2);
  vda_attn2<<<nwin, 1024, LDS2, stream>>>(x, wcatp, woutp, out);
}